// Round 3
// baseline (173.291 us; speedup 1.0000x reference)
//
#include <hip/hip_runtime.h>

typedef __attribute__((ext_vector_type(8))) short bf16x8;
typedef __attribute__((ext_vector_type(4))) float f32x4;
typedef __attribute__((ext_vector_type(4))) unsigned short u16x4;

__device__ __forceinline__ short f2bf(float f) {
  unsigned int u = __builtin_bit_cast(unsigned int, f);
  u += 0x7fffu + ((u >> 16) & 1u);  // RNE
  return (short)(u >> 16);
}

// ---------------- kernel 1: W^T bf16 prep ----------------
__global__ void prep_w(const float* __restrict__ Wq, const float* __restrict__ Wk,
                       const float* __restrict__ Wv, unsigned short* __restrict__ wt) {
  int idx = blockIdx.x * 256 + threadIdx.x;  // < 3*64*512
  int m = idx >> 15;
  int rem = idx & 32767;
  int n = rem >> 9;
  int k = rem & 511;
  const float* W = (m == 0) ? Wq : ((m == 1) ? Wk : Wv);
  wt[idx] = (unsigned short)f2bf(W[k * 64 + n]);
}

// ---------------- kernel 2: QKV projection (bf16 MFMA) ----------------
// grid (256, 3), 256 thr. mode 0 (Q): scaled by 0.125*log2(e). mode 2 (V):
// transposed output vt[b][dv][s], masked rows zeroed.
__global__ __launch_bounds__(256) void proj_kernel(
    const float* __restrict__ qx, const float* __restrict__ kx, const float* __restrict__ vx,
    const unsigned short* __restrict__ wt, const int* __restrict__ mask,
    const float* __restrict__ bqp, const float* __restrict__ bkp, const float* __restrict__ bvp,
    unsigned short* __restrict__ qo, unsigned short* __restrict__ ko,
    unsigned short* __restrict__ vo) {
  __shared__ unsigned short lds[64 * 256];  // 32 KB (W^T half; reused as V bounce)
  const int mode = blockIdx.y;
  const float* x = (mode == 0) ? qx : ((mode == 1) ? kx : vx);
  const float* bias = (mode == 0) ? bqp : ((mode == 1) ? bkp : bvp);
  const unsigned short* wtm = wt + mode * (64 * 512);
  const float osc = (mode == 0) ? 0.18033688011112042f : 1.0f;  // 0.125*log2(e)

  const int tid = threadIdx.x;
  const int w = tid >> 6, lane = tid & 63;
  const int g = lane >> 4, ln = lane & 15;
  const int rowbase = blockIdx.x * 128;

  const f32x4 fz = {0.f, 0.f, 0.f, 0.f};
  f32x4 acc[2][4];
#pragma unroll
  for (int mi = 0; mi < 2; ++mi)
#pragma unroll
    for (int nf = 0; nf < 4; ++nf) acc[mi][nf] = fz;

  for (int half = 0; half < 2; ++half) {
    __syncthreads();
#pragma unroll
    for (int i = 0; i < 8; ++i) {
      int c = tid + i * 256;
      int n = c >> 5, kc = c & 31;
      bf16x8 d = *reinterpret_cast<const bf16x8*>(wtm + n * 512 + half * 256 + kc * 8);
      int bo = (n * 512 + kc * 16) ^ ((n & 7) << 4);
      *reinterpret_cast<bf16x8*>(reinterpret_cast<char*>(lds) + bo) = d;
    }
    __syncthreads();
#pragma unroll
    for (int ks = 0; ks < 8; ++ks) {
      bf16x8 afrag[2];
#pragma unroll
      for (int mi = 0; mi < 2; ++mi) {
        int row = rowbase + w * 32 + mi * 16 + ln;
        const float4* ap = reinterpret_cast<const float4*>(
            x + (size_t)row * 512 + half * 256 + ks * 32 + g * 8);
        float4 a0 = ap[0], a1 = ap[1];
        bf16x8 af;
        af[0] = f2bf(a0.x); af[1] = f2bf(a0.y); af[2] = f2bf(a0.z); af[3] = f2bf(a0.w);
        af[4] = f2bf(a1.x); af[5] = f2bf(a1.y); af[6] = f2bf(a1.z); af[7] = f2bf(a1.w);
        afrag[mi] = af;
      }
#pragma unroll
      for (int nf = 0; nf < 4; ++nf) {
        int n = nf * 16 + ln;
        int bo = (n * 512 + ks * 64 + g * 16) ^ ((n & 7) << 4);
        bf16x8 bfrag = *reinterpret_cast<const bf16x8*>(reinterpret_cast<const char*>(lds) + bo);
        acc[0][nf] = __builtin_amdgcn_mfma_f32_16x16x32_bf16(afrag[0], bfrag, acc[0][nf], 0, 0, 0);
        acc[1][nf] = __builtin_amdgcn_mfma_f32_16x16x32_bf16(afrag[1], bfrag, acc[1][nf], 0, 0, 0);
      }
    }
  }

  float bc[4];
#pragma unroll
  for (int nf = 0; nf < 4; ++nf) bc[nf] = bias[nf * 16 + ln];

  if (mode < 2) {
    unsigned short* o = (mode == 0) ? qo : ko;
#pragma unroll
    for (int mi = 0; mi < 2; ++mi)
#pragma unroll
      for (int nf = 0; nf < 4; ++nf)
#pragma unroll
        for (int r = 0; r < 4; ++r) {
          int row = rowbase + w * 32 + mi * 16 + g * 4 + r;
          o[(size_t)row * 64 + nf * 16 + ln] = (unsigned short)f2bf((acc[mi][nf][r] + bc[nf]) * osc);
        }
  } else {
    // V: bounce through LDS, emit transposed vt[b][dv][s], zero masked rows
    __syncthreads();
#pragma unroll
    for (int mi = 0; mi < 2; ++mi)
#pragma unroll
      for (int nf = 0; nf < 4; ++nf)
#pragma unroll
        for (int r = 0; r < 4; ++r) {
          int srow = w * 32 + mi * 16 + g * 4 + r;
          lds[srow * 64 + nf * 16 + ln] = (unsigned short)f2bf(acc[mi][nf][r] + bc[nf]);
        }
    __syncthreads();
    int b = rowbase >> 12, s0 = rowbase & 4095;
    int dv = tid & 63, sc = tid >> 6;
#pragma unroll
    for (int i = 0; i < 4; ++i) {
      int sbase = s0 + sc * 32 + i * 8;
      const int* mrow = mask + b * 4096 + sbase;
      bf16x8 pack;
#pragma unroll
      for (int j = 0; j < 8; ++j) {
        short vv = (short)lds[(sc * 32 + i * 8 + j) * 64 + dv];
        pack[j] = mrow[j] ? vv : (short)0;
      }
      *reinterpret_cast<bf16x8*>(vo + (size_t)(b * 64 + dv) * 4096 + sbase) = pack;
    }
  }
}

// ---------------- kernel 3: flash attention (swapped QK^T, zero-shuffle P) ----
// grid (64, 8), 256 thr (4 waves). Q-tile 64 rows (16/wave), KV-tile 128.
// V staged in LDS with kv bit-permutation tau: slot x=c2*32+g*8+4h+lo holds
// physical kv p=c2*32+16h+4g+lo, so each lane's P values ARE its PV A-frag.
// LDS row 64 of vv = mask column (1.0/0.0) -> l comes out of a 5th PV frag.
// K fragments are read directly from global (identical across waves -> L1).
#define KVBLK 128
#define NTILES 32

__global__ __launch_bounds__(256) void attn_kernel(
    const unsigned short* __restrict__ qh, const unsigned short* __restrict__ kh,
    const unsigned short* __restrict__ vt, const int* __restrict__ mask,
    float* __restrict__ out) {
  __shared__ unsigned short vv[80 * 128];  // [dv 0..63 | 64=mask][kv-slot], 256B rows, 20 KB

  const int b = blockIdx.y;
  const int qbase = blockIdx.x * 64;
  const int tid = threadIdx.x;
  const int w = tid >> 6, lane = tid & 63;
  const int g = lane >> 4, ln = lane & 15;

  // Q as B-operand fragment (col = ln = q-row, k = 8g+j); pre-scaled by 0.125*log2e
  bf16x8 qa[2];
  {
    int row = qbase + w * 16 + ln;
    const unsigned short* qp = qh + (size_t)(b * 4096 + row) * 64;
    qa[0] = *reinterpret_cast<const bf16x8*>(qp + g * 8);
    qa[1] = *reinterpret_cast<const bf16x8*>(qp + 32 + g * 8);
  }

  const f32x4 fz = {0.f, 0.f, 0.f, 0.f};
  f32x4 accO[5];
#pragma unroll
  for (int nf = 0; nf < 5; ++nf) accO[nf] = fz;

  const unsigned short* khb = kh + (size_t)b * 4096 * 64;
  const unsigned short* vtb = vt + (size_t)b * 64 * 4096;

  // ---- staging helpers (V + mask only; K is global-direct) ----
  bf16x8 vreg[4];
  int mreg = 0;
  auto issueV = [&](int ti) {
    int kvbase = ti * KVBLK;
#pragma unroll
    for (int i = 0; i < 4; ++i) {
      int c = tid + i * 256;  // dv = c>>4, phys kv start = (c&15)*8
      vreg[i] = *reinterpret_cast<const bf16x8*>(vtb + (size_t)(c >> 4) * 4096 + kvbase + (c & 15) * 8);
    }
    if (tid < KVBLK) mreg = mask[b * 4096 + kvbase + tid];
  };
  auto commitV = [&]() {
#pragma unroll
    for (int i = 0; i < 4; ++i) {
      int c = tid + i * 256;
      int dv = c >> 4;
      int P0 = (c & 15) * 8;  // phys kv of element 0 (mult of 8 -> g even, h fixed)
      int c2 = P0 >> 5, h = (P0 >> 4) & 1, gg = (P0 >> 2) & 3;
      int x1 = 32 * c2 + 8 * gg + 4 * h;      // slot of phys run P0..P0+3
      int swz = (dv & 7) << 4;
      union { bf16x8 v; u16x4 h4[2]; } sp; sp.v = vreg[i];
      int bo1 = (dv * 256 + 2 * x1) ^ swz;
      int bo2 = (dv * 256 + 2 * x1 + 16) ^ swz;  // slot x1+8 <- phys P0+4..P0+7
      *reinterpret_cast<u16x4*>(reinterpret_cast<char*>(vv) + bo1) = sp.h4[0];
      *reinterpret_cast<u16x4*>(reinterpret_cast<char*>(vv) + bo2) = sp.h4[1];
    }
    if (tid < KVBLK) {
      int p = tid;
      int x = 32 * (p >> 5) + 8 * ((p >> 2) & 3) + 4 * ((p >> 4) & 1) + (p & 3);
      vv[64 * 128 + x] = mreg ? (unsigned short)0x3F80 : (unsigned short)0;  // row 64 swz==0
    }
  };

  // ---- prologue ----
  // K fragments for tile 0 (A-operand: row = kv = nf*16+ln, k = c2*32+g*8+j)
  bf16x8 kf[8][2];
#pragma unroll
  for (int nf = 0; nf < 8; ++nf)
#pragma unroll
    for (int c2 = 0; c2 < 2; ++c2)
      kf[nf][c2] = *reinterpret_cast<const bf16x8*>(
          khb + (size_t)(nf * 16 + ln) * 64 + c2 * 32 + g * 8);
  issueV(0);
  commitV();
  __syncthreads();

  for (int ti = 0; ti < NTILES; ++ti) {
    if (ti + 1 < NTILES) issueV(ti + 1);  // V loads in flight across compute

    // QK^T swapped: sacc[nf][r] = S[kv = nf*16+4g+r][q = ln]
    f32x4 sacc[8];
#pragma unroll
    for (int nf = 0; nf < 8; ++nf) sacc[nf] = fz;
#pragma unroll
    for (int c2 = 0; c2 < 2; ++c2)
#pragma unroll
      for (int nf = 0; nf < 8; ++nf)
        sacc[nf] = __builtin_amdgcn_mfma_f32_16x16x32_bf16(kf[nf][c2], qa[c2], sacc[nf], 0, 0, 0);

    // prefetch K for next tile (kf regs consumed at MFMA issue)
    if (ti + 1 < NTILES) {
      int kvb = (ti + 1) * KVBLK;
#pragma unroll
      for (int nf = 0; nf < 8; ++nf)
#pragma unroll
        for (int c2 = 0; c2 < 2; ++c2)
          kf[nf][c2] = *reinterpret_cast<const bf16x8*>(
              khb + (size_t)(kvb + nf * 16 + ln) * 64 + c2 * 32 + g * 8);
    }

    // p = exp2(s); pack to PV A-frags in-register (zero cross-lane via tau)
    unsigned int pw[4][4];  // pw[c2][t]: A-frag words
#pragma unroll
    for (int c2 = 0; c2 < 4; ++c2)
#pragma unroll
      for (int hh = 0; hh < 2; ++hh) {
        float p0 = __builtin_exp2f(sacc[2 * c2 + hh][0]);
        float p1 = __builtin_exp2f(sacc[2 * c2 + hh][1]);
        float p2 = __builtin_exp2f(sacc[2 * c2 + hh][2]);
        float p3 = __builtin_exp2f(sacc[2 * c2 + hh][3]);
        unsigned int w0, w1;
        asm("v_cvt_pk_bf16_f32 %0, %1, %2" : "=v"(w0) : "v"(p0), "v"(p1));
        asm("v_cvt_pk_bf16_f32 %0, %1, %2" : "=v"(w1) : "v"(p2), "v"(p3));
        pw[c2][2 * hh] = w0;
        pw[c2][2 * hh + 1] = w1;
      }

    // PV: O += P * V  (A = in-reg P, B = vv LDS frags; frag 4 = l column)
#pragma unroll
    for (int c2 = 0; c2 < 4; ++c2) {
      union { unsigned int u[4]; bf16x8 v; } pa;
      pa.u[0] = pw[c2][0]; pa.u[1] = pw[c2][1]; pa.u[2] = pw[c2][2]; pa.u[3] = pw[c2][3];
#pragma unroll
      for (int nf = 0; nf < 5; ++nf) {
        int dvr = nf * 16 + ln;
        int bo = (dvr * 256 + c2 * 64 + g * 16) ^ ((dvr & 7) << 4);
        bf16x8 vb = *reinterpret_cast<const bf16x8*>(reinterpret_cast<const char*>(vv) + bo);
        accO[nf] = __builtin_amdgcn_mfma_f32_16x16x32_bf16(pa.v, vb, accO[nf], 0, 0, 0);
      }
    }
    __syncthreads();                       // all waves done reading vv
    if (ti + 1 < NTILES) commitV();
    __syncthreads();
  }

  // epilogue: l = accO[4][r] at lanes ln==0 of same g; out fp32 [b][s][dv]
#pragma unroll
  for (int r = 0; r < 4; ++r) {
    float lv = __shfl(accO[4][r], lane & 48);
    float rv = __builtin_amdgcn_rcpf(lv);
    int row = qbase + w * 16 + g * 4 + r;
#pragma unroll
    for (int nf = 0; nf < 4; ++nf)
      out[(size_t)(b * 4096 + row) * 64 + nf * 16 + ln] = accO[nf][r] * rv;
  }
}

extern "C" void kernel_launch(void* const* d_in, const int* in_sizes, int n_in,
                              void* d_out, int out_size, void* d_ws, size_t ws_size,
                              hipStream_t stream) {
  const float* q = (const float*)d_in[0];
  const float* k = (const float*)d_in[1];
  const float* v = (const float*)d_in[2];
  const int* mask = (const int*)d_in[3];
  const float* Wq = (const float*)d_in[4];
  const float* bq = (const float*)d_in[5];
  const float* Wk = (const float*)d_in[6];
  const float* bk = (const float*)d_in[7];
  const float* Wv = (const float*)d_in[8];
  const float* bv = (const float*)d_in[9];

  unsigned short* wsu = (unsigned short*)d_ws;
  unsigned short* qh = wsu;                 // [8][4096][64] bf16 (pre-scaled)
  unsigned short* kh = qh + 2097152;        // [8][4096][64] bf16
  unsigned short* vt = kh + 2097152;        // [8][64][4096] bf16 (transposed, mask-zeroed)
  unsigned short* wt = vt + 2097152;        // [3][64][512] bf16

  prep_w<<<384, 256, 0, stream>>>(Wq, Wk, Wv, wt);
  proj_kernel<<<dim3(256, 3), 256, 0, stream>>>(q, k, v, wt, mask, bq, bk, bv, qh, kh, vt);
  attn_kernel<<<dim3(64, 8), 256, 0, stream>>>(qh, kh, vt, mask, (float*)d_out);
}

// Round 4
// 120.724 us; speedup vs baseline: 1.4354x; 1.4354x over previous
//
#include <hip/hip_runtime.h>

typedef __attribute__((ext_vector_type(8))) short bf16x8;
typedef __attribute__((ext_vector_type(4))) float f32x4;
typedef __attribute__((ext_vector_type(4))) unsigned short u16x4;

__device__ __forceinline__ short f2bf(float f) {
  unsigned int u = __builtin_bit_cast(unsigned int, f);
  u += 0x7fffu + ((u >> 16) & 1u);  // RNE
  return (short)(u >> 16);
}

// ---------------- kernel 1: W^T bf16 prep ----------------
__global__ void prep_w(const float* __restrict__ Wq, const float* __restrict__ Wk,
                       const float* __restrict__ Wv, unsigned short* __restrict__ wt) {
  int idx = blockIdx.x * 256 + threadIdx.x;  // < 3*64*512
  int m = idx >> 15;
  int rem = idx & 32767;
  int n = rem >> 9;
  int k = rem & 511;
  const float* W = (m == 0) ? Wq : ((m == 1) ? Wk : Wv);
  wt[idx] = (unsigned short)f2bf(W[k * 64 + n]);
}

// ---------------- kernel 2: QKV projection (bf16 MFMA) ----------------
// grid (256, 3), 256 thr. mode 0 (Q): scaled by 0.125*log2(e). mode 2 (V):
// transposed output vt[b][dv][s], masked rows zeroed.
__global__ __launch_bounds__(256) void proj_kernel(
    const float* __restrict__ qx, const float* __restrict__ kx, const float* __restrict__ vx,
    const unsigned short* __restrict__ wt, const int* __restrict__ mask,
    const float* __restrict__ bqp, const float* __restrict__ bkp, const float* __restrict__ bvp,
    unsigned short* __restrict__ qo, unsigned short* __restrict__ ko,
    unsigned short* __restrict__ vo) {
  __shared__ unsigned short lds[64 * 256];  // 32 KB (W^T half; reused as V bounce)
  const int mode = blockIdx.y;
  const float* x = (mode == 0) ? qx : ((mode == 1) ? kx : vx);
  const float* bias = (mode == 0) ? bqp : ((mode == 1) ? bkp : bvp);
  const unsigned short* wtm = wt + mode * (64 * 512);
  const float osc = (mode == 0) ? 0.18033688011112042f : 1.0f;  // 0.125*log2(e)

  const int tid = threadIdx.x;
  const int w = tid >> 6, lane = tid & 63;
  const int g = lane >> 4, ln = lane & 15;
  const int rowbase = blockIdx.x * 128;

  const f32x4 fz = {0.f, 0.f, 0.f, 0.f};
  f32x4 acc[2][4];
#pragma unroll
  for (int mi = 0; mi < 2; ++mi)
#pragma unroll
    for (int nf = 0; nf < 4; ++nf) acc[mi][nf] = fz;

  for (int half = 0; half < 2; ++half) {
    __syncthreads();
#pragma unroll
    for (int i = 0; i < 8; ++i) {
      int c = tid + i * 256;
      int n = c >> 5, kc = c & 31;
      bf16x8 d = *reinterpret_cast<const bf16x8*>(wtm + n * 512 + half * 256 + kc * 8);
      int bo = (n * 512 + kc * 16) ^ ((n & 7) << 4);
      *reinterpret_cast<bf16x8*>(reinterpret_cast<char*>(lds) + bo) = d;
    }
    __syncthreads();
#pragma unroll
    for (int ks = 0; ks < 8; ++ks) {
      bf16x8 afrag[2];
#pragma unroll
      for (int mi = 0; mi < 2; ++mi) {
        int row = rowbase + w * 32 + mi * 16 + ln;
        const float4* ap = reinterpret_cast<const float4*>(
            x + (size_t)row * 512 + half * 256 + ks * 32 + g * 8);
        float4 a0 = ap[0], a1 = ap[1];
        bf16x8 af;
        af[0] = f2bf(a0.x); af[1] = f2bf(a0.y); af[2] = f2bf(a0.z); af[3] = f2bf(a0.w);
        af[4] = f2bf(a1.x); af[5] = f2bf(a1.y); af[6] = f2bf(a1.z); af[7] = f2bf(a1.w);
        afrag[mi] = af;
      }
#pragma unroll
      for (int nf = 0; nf < 4; ++nf) {
        int n = nf * 16 + ln;
        int bo = (n * 512 + ks * 64 + g * 16) ^ ((n & 7) << 4);
        bf16x8 bfrag = *reinterpret_cast<const bf16x8*>(reinterpret_cast<const char*>(lds) + bo);
        acc[0][nf] = __builtin_amdgcn_mfma_f32_16x16x32_bf16(afrag[0], bfrag, acc[0][nf], 0, 0, 0);
        acc[1][nf] = __builtin_amdgcn_mfma_f32_16x16x32_bf16(afrag[1], bfrag, acc[1][nf], 0, 0, 0);
      }
    }
  }

  float bc[4];
#pragma unroll
  for (int nf = 0; nf < 4; ++nf) bc[nf] = bias[nf * 16 + ln];

  if (mode < 2) {
    unsigned short* o = (mode == 0) ? qo : ko;
#pragma unroll
    for (int mi = 0; mi < 2; ++mi)
#pragma unroll
      for (int nf = 0; nf < 4; ++nf)
#pragma unroll
        for (int r = 0; r < 4; ++r) {
          int row = rowbase + w * 32 + mi * 16 + g * 4 + r;
          o[(size_t)row * 64 + nf * 16 + ln] = (unsigned short)f2bf((acc[mi][nf][r] + bc[nf]) * osc);
        }
  } else {
    // V: bounce through LDS, emit transposed vt[b][dv][s], zero masked rows
    __syncthreads();
#pragma unroll
    for (int mi = 0; mi < 2; ++mi)
#pragma unroll
      for (int nf = 0; nf < 4; ++nf)
#pragma unroll
        for (int r = 0; r < 4; ++r) {
          int srow = w * 32 + mi * 16 + g * 4 + r;
          lds[srow * 64 + nf * 16 + ln] = (unsigned short)f2bf(acc[mi][nf][r] + bc[nf]);
        }
    __syncthreads();
    int b = rowbase >> 12, s0 = rowbase & 4095;
    int dv = tid & 63, sc = tid >> 6;
#pragma unroll
    for (int i = 0; i < 4; ++i) {
      int sbase = s0 + sc * 32 + i * 8;
      const int* mrow = mask + b * 4096 + sbase;
      bf16x8 pack;
#pragma unroll
      for (int j = 0; j < 8; ++j) {
        short vv = (short)lds[(sc * 32 + i * 8 + j) * 64 + dv];
        pack[j] = mrow[j] ? vv : (short)0;
      }
      *reinterpret_cast<bf16x8*>(vo + (size_t)(b * 64 + dv) * 4096 + sbase) = pack;
    }
  }
}

// ---------------- kernel 3: flash attention ----------------
// grid (32, 8), 256 thr (4 waves). Wave owns 32 q-rows (2 B-frags) -> every
// K/V LDS fragment read feeds 2 MFMAs. K [kv][dk] LDS-staged swizzled;
// V tau-permuted (kv slot x=c2*32+g*8+4h+lo <- phys c2*32+16h+4g+lo) so each
// lane's exp2'd P values ARE its PV A-frag (zero cross-lane). vv row 64 =
// mask column -> l from 5th PV fragment. Double-buffered, ONE barrier/tile.
#define KVBLK 128
#define NTILES 32

__global__ __launch_bounds__(256) void attn_kernel(
    const unsigned short* __restrict__ qh, const unsigned short* __restrict__ kh,
    const unsigned short* __restrict__ vt, const int* __restrict__ mask,
    float* __restrict__ out) {
  __shared__ unsigned short kt[2][KVBLK * 64];  // 16 KB each, [kv][dk] swizzled
  __shared__ unsigned short vv[2][80 * 128];    // 20 KB each, 256B rows

  const int b = blockIdx.y;
  const int qbase = blockIdx.x * 128;
  const int tid = threadIdx.x;
  const int w = tid >> 6, lane = tid & 63;
  const int g = lane >> 4, ln = lane & 15;

  // zero junk rows 65..79 of both vv buffers (read by the l-fragment MFMA)
  for (int i = tid; i < 15 * 128; i += 256) {
    vv[0][65 * 128 + i] = 0;
    vv[1][65 * 128 + i] = 0;
  }

  // Q B-frags (col = ln = q-row, k = 8g+j); qh pre-scaled by 0.125*log2e
  bf16x8 qa[2][2];
#pragma unroll
  for (int qf = 0; qf < 2; ++qf) {
    int row = qbase + w * 32 + qf * 16 + ln;
    const unsigned short* qp = qh + (size_t)(b * 4096 + row) * 64;
    qa[qf][0] = *reinterpret_cast<const bf16x8*>(qp + g * 8);
    qa[qf][1] = *reinterpret_cast<const bf16x8*>(qp + 32 + g * 8);
  }

  const f32x4 fz = {0.f, 0.f, 0.f, 0.f};
  f32x4 accO[2][5];
#pragma unroll
  for (int qf = 0; qf < 2; ++qf)
#pragma unroll
    for (int nf = 0; nf < 5; ++nf) accO[qf][nf] = fz;

  const unsigned short* khb = kh + (size_t)b * 4096 * 64;
  const unsigned short* vtb = vt + (size_t)b * 64 * 4096;

  // ---- staging (register prefetch -> swizzled LDS) ----
  bf16x8 kreg[4], vreg[4];
  int mreg = 0;
  auto issue = [&](int ti) {
    int kvbase = ti * KVBLK;
#pragma unroll
    for (int i = 0; i < 4; ++i) {
      int c = tid + i * 256;  // V: dv = c>>4, phys kv start (c&15)*8
      vreg[i] = *reinterpret_cast<const bf16x8*>(vtb + (size_t)(c >> 4) * 4096 + kvbase + (c & 15) * 8);
      // K: row = c>>3 (kv), col16 = c&7
      kreg[i] = *reinterpret_cast<const bf16x8*>(khb + (size_t)(kvbase + (c >> 3)) * 64 + (c & 7) * 8);
    }
    if (tid < KVBLK) mreg = mask[b * 4096 + kvbase + tid];
  };
  auto commit = [&](int bs) {
#pragma unroll
    for (int i = 0; i < 4; ++i) {
      int c = tid + i * 256;
      // K swizzled store
      int kbo = ((c >> 3) * 128 + (c & 7) * 16) ^ (((c >> 3) & 7) << 4);
      *reinterpret_cast<bf16x8*>(reinterpret_cast<char*>(kt[bs]) + kbo) = kreg[i];
      // V tau-permuted store (two 8B halves)
      int dv = c >> 4;
      int P0 = (c & 15) * 8;
      int c2 = P0 >> 5, h = (P0 >> 4) & 1, gg = (P0 >> 2) & 3;
      int x1 = 32 * c2 + 8 * gg + 4 * h;
      int swz = (dv & 7) << 4;
      union { bf16x8 v; u16x4 h4[2]; } sp; sp.v = vreg[i];
      *reinterpret_cast<u16x4*>(reinterpret_cast<char*>(vv[bs]) + ((dv * 256 + 2 * x1) ^ swz)) = sp.h4[0];
      *reinterpret_cast<u16x4*>(reinterpret_cast<char*>(vv[bs]) + ((dv * 256 + 2 * x1 + 16) ^ swz)) = sp.h4[1];
    }
    if (tid < KVBLK) {
      int p = tid;
      int x = 32 * (p >> 5) + 8 * ((p >> 2) & 3) + 4 * ((p >> 4) & 1) + (p & 3);
      vv[bs][64 * 128 + x] = mreg ? (unsigned short)0x3F80 : (unsigned short)0;
    }
  };

  // ---- prologue ----
  issue(0);
  commit(0);
  __syncthreads();
  int cur = 0;

  for (int ti = 0; ti < NTILES; ++ti) {
    if (ti + 1 < NTILES) issue(ti + 1);  // loads in flight across compute

    // QK^T swapped: s{qf}[nf][r] = S[kv = nf*16+4g+r][q = qf*16+ln]
    f32x4 s0[8], s1[8];
#pragma unroll
    for (int nf = 0; nf < 8; ++nf) { s0[nf] = fz; s1[nf] = fz; }
#pragma unroll
    for (int c2 = 0; c2 < 2; ++c2)
#pragma unroll
      for (int nf = 0; nf < 8; ++nf) {
        int kvr = nf * 16 + ln;
        int bo = (kvr * 128 + c2 * 64 + g * 16) ^ ((kvr & 7) << 4);
        bf16x8 kf = *reinterpret_cast<const bf16x8*>(reinterpret_cast<const char*>(kt[cur]) + bo);
        s0[nf] = __builtin_amdgcn_mfma_f32_16x16x32_bf16(kf, qa[0][c2], s0[nf], 0, 0, 0);
        s1[nf] = __builtin_amdgcn_mfma_f32_16x16x32_bf16(kf, qa[1][c2], s1[nf], 0, 0, 0);
      }

    // p = exp2(s); pack to PV A-frag words (zero cross-lane via tau)
    unsigned int pw[2][4][4];
#pragma unroll
    for (int c2 = 0; c2 < 4; ++c2)
#pragma unroll
      for (int hh = 0; hh < 2; ++hh) {
        {
          float p0 = __builtin_exp2f(s0[2 * c2 + hh][0]);
          float p1 = __builtin_exp2f(s0[2 * c2 + hh][1]);
          float p2 = __builtin_exp2f(s0[2 * c2 + hh][2]);
          float p3 = __builtin_exp2f(s0[2 * c2 + hh][3]);
          unsigned int w0, w1;
          asm("v_cvt_pk_bf16_f32 %0, %1, %2" : "=v"(w0) : "v"(p0), "v"(p1));
          asm("v_cvt_pk_bf16_f32 %0, %1, %2" : "=v"(w1) : "v"(p2), "v"(p3));
          pw[0][c2][2 * hh] = w0;
          pw[0][c2][2 * hh + 1] = w1;
        }
        {
          float p0 = __builtin_exp2f(s1[2 * c2 + hh][0]);
          float p1 = __builtin_exp2f(s1[2 * c2 + hh][1]);
          float p2 = __builtin_exp2f(s1[2 * c2 + hh][2]);
          float p3 = __builtin_exp2f(s1[2 * c2 + hh][3]);
          unsigned int w0, w1;
          asm("v_cvt_pk_bf16_f32 %0, %1, %2" : "=v"(w0) : "v"(p0), "v"(p1));
          asm("v_cvt_pk_bf16_f32 %0, %1, %2" : "=v"(w1) : "v"(p2), "v"(p3));
          pw[1][c2][2 * hh] = w0;
          pw[1][c2][2 * hh + 1] = w1;
        }
      }

    // PV: O'[q][dv] += P·V  (A = in-reg P, B = vv frags; nf==4 -> l column)
#pragma unroll
    for (int c2 = 0; c2 < 4; ++c2) {
      union { unsigned int u[4]; bf16x8 v; } pa0, pa1;
#pragma unroll
      for (int t = 0; t < 4; ++t) { pa0.u[t] = pw[0][c2][t]; pa1.u[t] = pw[1][c2][t]; }
#pragma unroll
      for (int nf = 0; nf < 5; ++nf) {
        int dvr = nf * 16 + ln;
        int bo = (dvr * 256 + c2 * 64 + g * 16) ^ ((dvr & 7) << 4);
        bf16x8 vb = *reinterpret_cast<const bf16x8*>(reinterpret_cast<const char*>(vv[cur]) + bo);
        accO[0][nf] = __builtin_amdgcn_mfma_f32_16x16x32_bf16(pa0.v, vb, accO[0][nf], 0, 0, 0);
        accO[1][nf] = __builtin_amdgcn_mfma_f32_16x16x32_bf16(pa1.v, vb, accO[1][nf], 0, 0, 0);
      }
    }

    if (ti + 1 < NTILES) commit(cur ^ 1);
    __syncthreads();
    cur ^= 1;
  }

  // epilogue: l at col ln==0 of the l-fragment; out fp32 [b][s][dv]
#pragma unroll
  for (int qf = 0; qf < 2; ++qf)
#pragma unroll
    for (int r = 0; r < 4; ++r) {
      float lv = __shfl(accO[qf][4][r], lane & 48);
      float rv = __builtin_amdgcn_rcpf(lv);
      int row = qbase + w * 32 + qf * 16 + g * 4 + r;
#pragma unroll
      for (int nf = 0; nf < 4; ++nf)
        out[(size_t)(b * 4096 + row) * 64 + nf * 16 + ln] = accO[qf][nf][r] * rv;
    }
}

extern "C" void kernel_launch(void* const* d_in, const int* in_sizes, int n_in,
                              void* d_out, int out_size, void* d_ws, size_t ws_size,
                              hipStream_t stream) {
  const float* q = (const float*)d_in[0];
  const float* k = (const float*)d_in[1];
  const float* v = (const float*)d_in[2];
  const int* mask = (const int*)d_in[3];
  const float* Wq = (const float*)d_in[4];
  const float* bq = (const float*)d_in[5];
  const float* Wk = (const float*)d_in[6];
  const float* bk = (const float*)d_in[7];
  const float* Wv = (const float*)d_in[8];
  const float* bv = (const float*)d_in[9];

  unsigned short* wsu = (unsigned short*)d_ws;
  unsigned short* qh = wsu;                 // [8][4096][64] bf16 (pre-scaled)
  unsigned short* kh = qh + 2097152;        // [8][4096][64] bf16
  unsigned short* vt = kh + 2097152;        // [8][64][4096] bf16 (transposed, mask-zeroed)
  unsigned short* wt = vt + 2097152;        // [3][64][512] bf16

  prep_w<<<384, 256, 0, stream>>>(Wq, Wk, Wv, wt);
  proj_kernel<<<dim3(256, 3), 256, 0, stream>>>(q, k, v, wt, mask, bq, bk, bv, qh, kh, vt);
  attn_kernel<<<dim3(32, 8), 256, 0, stream>>>(qh, kh, vt, mask, (float*)d_out);
}

// Round 5
// 111.833 us; speedup vs baseline: 1.5496x; 1.0795x over previous
//
#include <hip/hip_runtime.h>

typedef __attribute__((ext_vector_type(8))) short bf16x8;
typedef __attribute__((ext_vector_type(4))) float f32x4;
typedef __attribute__((ext_vector_type(4))) unsigned short u16x4;

__device__ __forceinline__ short f2bf(float f) {
  unsigned int u = __builtin_bit_cast(unsigned int, f);
  u += 0x7fffu + ((u >> 16) & 1u);  // RNE
  return (short)(u >> 16);
}

// ---------------- kernel 1: W^T bf16 prep ----------------
__global__ void prep_w(const float* __restrict__ Wq, const float* __restrict__ Wk,
                       const float* __restrict__ Wv, unsigned short* __restrict__ wt) {
  int idx = blockIdx.x * 256 + threadIdx.x;  // < 3*64*512
  int m = idx >> 15;
  int rem = idx & 32767;
  int n = rem >> 9;
  int k = rem & 511;
  const float* W = (m == 0) ? Wq : ((m == 1) ? Wk : Wv);
  wt[idx] = (unsigned short)f2bf(W[k * 64 + n]);
}

// ---------------- kernel 2: QKV projection (bf16 MFMA) ----------------
// grid (256, 3), 256 thr. mode 0 (Q): scaled by 0.125*log2(e). mode 2 (V):
// transposed output vt[b][dv][s], masked rows zeroed.
__global__ __launch_bounds__(256) void proj_kernel(
    const float* __restrict__ qx, const float* __restrict__ kx, const float* __restrict__ vx,
    const unsigned short* __restrict__ wt, const int* __restrict__ mask,
    const float* __restrict__ bqp, const float* __restrict__ bkp, const float* __restrict__ bvp,
    unsigned short* __restrict__ qo, unsigned short* __restrict__ ko,
    unsigned short* __restrict__ vo) {
  __shared__ unsigned short lds[64 * 256];  // 32 KB (W^T half; reused as V bounce)
  const int mode = blockIdx.y;
  const float* x = (mode == 0) ? qx : ((mode == 1) ? kx : vx);
  const float* bias = (mode == 0) ? bqp : ((mode == 1) ? bkp : bvp);
  const unsigned short* wtm = wt + mode * (64 * 512);
  const float osc = (mode == 0) ? 0.18033688011112042f : 1.0f;  // 0.125*log2(e)

  const int tid = threadIdx.x;
  const int w = tid >> 6, lane = tid & 63;
  const int g = lane >> 4, ln = lane & 15;
  const int rowbase = blockIdx.x * 128;

  const f32x4 fz = {0.f, 0.f, 0.f, 0.f};
  f32x4 acc[2][4];
#pragma unroll
  for (int mi = 0; mi < 2; ++mi)
#pragma unroll
    for (int nf = 0; nf < 4; ++nf) acc[mi][nf] = fz;

  for (int half = 0; half < 2; ++half) {
    __syncthreads();
#pragma unroll
    for (int i = 0; i < 8; ++i) {
      int c = tid + i * 256;
      int n = c >> 5, kc = c & 31;
      bf16x8 d = *reinterpret_cast<const bf16x8*>(wtm + n * 512 + half * 256 + kc * 8);
      int bo = (n * 512 + kc * 16) ^ ((n & 7) << 4);
      *reinterpret_cast<bf16x8*>(reinterpret_cast<char*>(lds) + bo) = d;
    }
    __syncthreads();
#pragma unroll
    for (int ks = 0; ks < 8; ++ks) {
      bf16x8 afrag[2];
#pragma unroll
      for (int mi = 0; mi < 2; ++mi) {
        int row = rowbase + w * 32 + mi * 16 + ln;
        const float4* ap = reinterpret_cast<const float4*>(
            x + (size_t)row * 512 + half * 256 + ks * 32 + g * 8);
        float4 a0 = ap[0], a1 = ap[1];
        bf16x8 af;
        af[0] = f2bf(a0.x); af[1] = f2bf(a0.y); af[2] = f2bf(a0.z); af[3] = f2bf(a0.w);
        af[4] = f2bf(a1.x); af[5] = f2bf(a1.y); af[6] = f2bf(a1.z); af[7] = f2bf(a1.w);
        afrag[mi] = af;
      }
#pragma unroll
      for (int nf = 0; nf < 4; ++nf) {
        int n = nf * 16 + ln;
        int bo = (n * 512 + ks * 64 + g * 16) ^ ((n & 7) << 4);
        bf16x8 bfrag = *reinterpret_cast<const bf16x8*>(reinterpret_cast<const char*>(lds) + bo);
        acc[0][nf] = __builtin_amdgcn_mfma_f32_16x16x32_bf16(afrag[0], bfrag, acc[0][nf], 0, 0, 0);
        acc[1][nf] = __builtin_amdgcn_mfma_f32_16x16x32_bf16(afrag[1], bfrag, acc[1][nf], 0, 0, 0);
      }
    }
  }

  float bc[4];
#pragma unroll
  for (int nf = 0; nf < 4; ++nf) bc[nf] = bias[nf * 16 + ln];

  if (mode < 2) {
    unsigned short* o = (mode == 0) ? qo : ko;
#pragma unroll
    for (int mi = 0; mi < 2; ++mi)
#pragma unroll
      for (int nf = 0; nf < 4; ++nf)
#pragma unroll
        for (int r = 0; r < 4; ++r) {
          int row = rowbase + w * 32 + mi * 16 + g * 4 + r;
          o[(size_t)row * 64 + nf * 16 + ln] = (unsigned short)f2bf((acc[mi][nf][r] + bc[nf]) * osc);
        }
  } else {
    // V: bounce through LDS, emit transposed vt[b][dv][s], zero masked rows
    __syncthreads();
#pragma unroll
    for (int mi = 0; mi < 2; ++mi)
#pragma unroll
      for (int nf = 0; nf < 4; ++nf)
#pragma unroll
        for (int r = 0; r < 4; ++r) {
          int srow = w * 32 + mi * 16 + g * 4 + r;
          lds[srow * 64 + nf * 16 + ln] = (unsigned short)f2bf(acc[mi][nf][r] + bc[nf]);
        }
    __syncthreads();
    int b = rowbase >> 12, s0 = rowbase & 4095;
    int dv = tid & 63, sc = tid >> 6;
#pragma unroll
    for (int i = 0; i < 4; ++i) {
      int sbase = s0 + sc * 32 + i * 8;
      const int* mrow = mask + b * 4096 + sbase;
      bf16x8 pack;
#pragma unroll
      for (int j = 0; j < 8; ++j) {
        short vv = (short)lds[(sc * 32 + i * 8 + j) * 64 + dv];
        pack[j] = mrow[j] ? vv : (short)0;
      }
      *reinterpret_cast<bf16x8*>(vo + (size_t)(b * 64 + dv) * 4096 + sbase) = pack;
    }
  }
}

// ---------------- kernel 3: flash attention (KV-split partials) ----------------
// grid (32, 8, 2), 256 thr (4 waves). Wave owns 32 q-rows (2 B-frags).
// blockIdx.z selects KV half [z*2048, z*2048+2048); partial O (raw sums) and
// partial l are written out; combine_kernel merges. No-max softmax makes the
// partials purely additive. 2 blocks/CU = 2 waves/SIMD for latency hiding.
#define KVBLK 128
#define NT 16

__global__ __launch_bounds__(256, 2) void attn_kernel(
    const unsigned short* __restrict__ qh, const unsigned short* __restrict__ kh,
    const unsigned short* __restrict__ vt, const int* __restrict__ mask,
    float* __restrict__ out0, float* __restrict__ out1,
    float* __restrict__ l0p, float* __restrict__ l1p) {
  __shared__ unsigned short kt[2][KVBLK * 64];  // 16 KB each, [kv][dk] swizzled
  __shared__ unsigned short vv[2][80 * 128];    // 20 KB each, 256B rows

  const int b = blockIdx.y;
  const int z = blockIdx.z;
  const int kv0 = z * (NT * KVBLK);
  float* __restrict__ optr = z ? out1 : out0;
  float* __restrict__ lptr = z ? l1p : l0p;
  const int qbase = blockIdx.x * 128;
  const int tid = threadIdx.x;
  const int w = tid >> 6, lane = tid & 63;
  const int g = lane >> 4, ln = lane & 15;

  // zero junk rows 65..79 of both vv buffers (read by the l-fragment MFMA)
  for (int i = tid; i < 15 * 128; i += 256) {
    vv[0][65 * 128 + i] = 0;
    vv[1][65 * 128 + i] = 0;
  }

  // Q B-frags (col = ln = q-row, k = 8g+j); qh pre-scaled by 0.125*log2e
  bf16x8 qa[2][2];
#pragma unroll
  for (int qf = 0; qf < 2; ++qf) {
    int row = qbase + w * 32 + qf * 16 + ln;
    const unsigned short* qp = qh + (size_t)(b * 4096 + row) * 64;
    qa[qf][0] = *reinterpret_cast<const bf16x8*>(qp + g * 8);
    qa[qf][1] = *reinterpret_cast<const bf16x8*>(qp + 32 + g * 8);
  }

  const f32x4 fz = {0.f, 0.f, 0.f, 0.f};
  f32x4 accO[2][5];
#pragma unroll
  for (int qf = 0; qf < 2; ++qf)
#pragma unroll
    for (int nf = 0; nf < 5; ++nf) accO[qf][nf] = fz;

  const unsigned short* khb = kh + (size_t)b * 4096 * 64;
  const unsigned short* vtb = vt + (size_t)b * 64 * 4096;

  // ---- staging (register prefetch -> swizzled LDS) ----
  bf16x8 kreg[4], vreg[4];
  int mreg = 0;
  auto issue = [&](int ti) {
    int kvbase = kv0 + ti * KVBLK;
#pragma unroll
    for (int i = 0; i < 4; ++i) {
      int c = tid + i * 256;  // V: dv = c>>4, phys kv start (c&15)*8
      vreg[i] = *reinterpret_cast<const bf16x8*>(vtb + (size_t)(c >> 4) * 4096 + kvbase + (c & 15) * 8);
      // K: row = c>>3 (kv), col16 = c&7
      kreg[i] = *reinterpret_cast<const bf16x8*>(khb + (size_t)(kvbase + (c >> 3)) * 64 + (c & 7) * 8);
    }
    if (tid < KVBLK) mreg = mask[b * 4096 + kvbase + tid];
  };
  auto commit = [&](int bs) {
#pragma unroll
    for (int i = 0; i < 4; ++i) {
      int c = tid + i * 256;
      // K swizzled store
      int kbo = ((c >> 3) * 128 + (c & 7) * 16) ^ (((c >> 3) & 7) << 4);
      *reinterpret_cast<bf16x8*>(reinterpret_cast<char*>(kt[bs]) + kbo) = kreg[i];
      // V tau-permuted store (two 8B halves)
      int dv = c >> 4;
      int P0 = (c & 15) * 8;
      int c2 = P0 >> 5, h = (P0 >> 4) & 1, gg = (P0 >> 2) & 3;
      int x1 = 32 * c2 + 8 * gg + 4 * h;
      int swz = (dv & 7) << 4;
      union { bf16x8 v; u16x4 h4[2]; } sp; sp.v = vreg[i];
      *reinterpret_cast<u16x4*>(reinterpret_cast<char*>(vv[bs]) + ((dv * 256 + 2 * x1) ^ swz)) = sp.h4[0];
      *reinterpret_cast<u16x4*>(reinterpret_cast<char*>(vv[bs]) + ((dv * 256 + 2 * x1 + 16) ^ swz)) = sp.h4[1];
    }
    if (tid < KVBLK) {
      int p = tid;
      int x = 32 * (p >> 5) + 8 * ((p >> 2) & 3) + 4 * ((p >> 4) & 1) + (p & 3);
      vv[bs][64 * 128 + x] = mreg ? (unsigned short)0x3F80 : (unsigned short)0;
    }
  };

  // ---- prologue ----
  issue(0);
  commit(0);
  __syncthreads();
  int cur = 0;

  for (int ti = 0; ti < NT; ++ti) {
    if (ti + 1 < NT) issue(ti + 1);  // loads in flight across compute

    // QK^T swapped: s{qf}[nf][r] = S[kv = nf*16+4g+r][q = qf*16+ln]
    f32x4 s0[8], s1[8];
#pragma unroll
    for (int nf = 0; nf < 8; ++nf) { s0[nf] = fz; s1[nf] = fz; }
    __builtin_amdgcn_s_setprio(1);
#pragma unroll
    for (int c2 = 0; c2 < 2; ++c2)
#pragma unroll
      for (int nf = 0; nf < 8; ++nf) {
        int kvr = nf * 16 + ln;
        int bo = (kvr * 128 + c2 * 64 + g * 16) ^ ((kvr & 7) << 4);
        bf16x8 kf = *reinterpret_cast<const bf16x8*>(reinterpret_cast<const char*>(kt[cur]) + bo);
        s0[nf] = __builtin_amdgcn_mfma_f32_16x16x32_bf16(kf, qa[0][c2], s0[nf], 0, 0, 0);
        s1[nf] = __builtin_amdgcn_mfma_f32_16x16x32_bf16(kf, qa[1][c2], s1[nf], 0, 0, 0);
      }
    __builtin_amdgcn_s_setprio(0);

    // p = exp2(s); pack to PV A-frag words (zero cross-lane via tau)
    unsigned int pw[2][4][4];
#pragma unroll
    for (int c2 = 0; c2 < 4; ++c2)
#pragma unroll
      for (int hh = 0; hh < 2; ++hh) {
        {
          float p0 = __builtin_exp2f(s0[2 * c2 + hh][0]);
          float p1 = __builtin_exp2f(s0[2 * c2 + hh][1]);
          float p2 = __builtin_exp2f(s0[2 * c2 + hh][2]);
          float p3 = __builtin_exp2f(s0[2 * c2 + hh][3]);
          unsigned int w0, w1;
          asm("v_cvt_pk_bf16_f32 %0, %1, %2" : "=v"(w0) : "v"(p0), "v"(p1));
          asm("v_cvt_pk_bf16_f32 %0, %1, %2" : "=v"(w1) : "v"(p2), "v"(p3));
          pw[0][c2][2 * hh] = w0;
          pw[0][c2][2 * hh + 1] = w1;
        }
        {
          float p0 = __builtin_exp2f(s1[2 * c2 + hh][0]);
          float p1 = __builtin_exp2f(s1[2 * c2 + hh][1]);
          float p2 = __builtin_exp2f(s1[2 * c2 + hh][2]);
          float p3 = __builtin_exp2f(s1[2 * c2 + hh][3]);
          unsigned int w0, w1;
          asm("v_cvt_pk_bf16_f32 %0, %1, %2" : "=v"(w0) : "v"(p0), "v"(p1));
          asm("v_cvt_pk_bf16_f32 %0, %1, %2" : "=v"(w1) : "v"(p2), "v"(p3));
          pw[1][c2][2 * hh] = w0;
          pw[1][c2][2 * hh + 1] = w1;
        }
      }

    // PV: O'[q][dv] += P·V  (A = in-reg P, B = vv frags; nf==4 -> l column)
    __builtin_amdgcn_s_setprio(1);
#pragma unroll
    for (int c2 = 0; c2 < 4; ++c2) {
      union { unsigned int u[4]; bf16x8 v; } pa0, pa1;
#pragma unroll
      for (int t = 0; t < 4; ++t) { pa0.u[t] = pw[0][c2][t]; pa1.u[t] = pw[1][c2][t]; }
#pragma unroll
      for (int nf = 0; nf < 5; ++nf) {
        int dvr = nf * 16 + ln;
        int bo = (dvr * 256 + c2 * 64 + g * 16) ^ ((dvr & 7) << 4);
        bf16x8 vb = *reinterpret_cast<const bf16x8*>(reinterpret_cast<const char*>(vv[cur]) + bo);
        accO[0][nf] = __builtin_amdgcn_mfma_f32_16x16x32_bf16(pa0.v, vb, accO[0][nf], 0, 0, 0);
        accO[1][nf] = __builtin_amdgcn_mfma_f32_16x16x32_bf16(pa1.v, vb, accO[1][nf], 0, 0, 0);
      }
    }
    __builtin_amdgcn_s_setprio(0);

    if (ti + 1 < NT) commit(cur ^ 1);
    __syncthreads();
    cur ^= 1;
  }

  // epilogue: raw partial O; l-frag valid at ln==0 lanes (dvr=64 column)
#pragma unroll
  for (int qf = 0; qf < 2; ++qf)
#pragma unroll
    for (int r = 0; r < 4; ++r) {
      int grow = b * 4096 + qbase + w * 32 + qf * 16 + g * 4 + r;
#pragma unroll
      for (int nf = 0; nf < 4; ++nf)
        optr[(size_t)grow * 64 + nf * 16 + ln] = accO[qf][nf][r];
      if (ln == 0) lptr[grow] = accO[qf][4][r];
    }
}

// ---------------- kernel 4: combine partials ----------------
// out = (O0 + O1) / (l0 + l1); 524288 float4s, grid 2048 x 256
__global__ __launch_bounds__(256) void combine_kernel(
    float* __restrict__ out, const float* __restrict__ po1,
    const float* __restrict__ l0p, const float* __restrict__ l1p) {
  int idx = blockIdx.x * 256 + threadIdx.x;
  int row = idx >> 4;  // 16 float4 per 64-col row
  float rl = 1.0f / (l0p[row] + l1p[row]);
  float4 a = reinterpret_cast<float4*>(out)[idx];
  float4 c = reinterpret_cast<const float4*>(po1)[idx];
  a.x = (a.x + c.x) * rl;
  a.y = (a.y + c.y) * rl;
  a.z = (a.z + c.z) * rl;
  a.w = (a.w + c.w) * rl;
  reinterpret_cast<float4*>(out)[idx] = a;
}

extern "C" void kernel_launch(void* const* d_in, const int* in_sizes, int n_in,
                              void* d_out, int out_size, void* d_ws, size_t ws_size,
                              hipStream_t stream) {
  const float* q = (const float*)d_in[0];
  const float* k = (const float*)d_in[1];
  const float* v = (const float*)d_in[2];
  const int* mask = (const int*)d_in[3];
  const float* Wq = (const float*)d_in[4];
  const float* bq = (const float*)d_in[5];
  const float* Wk = (const float*)d_in[6];
  const float* bk = (const float*)d_in[7];
  const float* Wv = (const float*)d_in[8];
  const float* bv = (const float*)d_in[9];

  char* wsb = (char*)d_ws;
  unsigned short* qh = (unsigned short*)(wsb);                    // 4 MiB
  unsigned short* kh = (unsigned short*)(wsb + (4u << 20));       // 4 MiB
  unsigned short* vt = (unsigned short*)(wsb + (8u << 20));       // 4 MiB
  unsigned short* wt = (unsigned short*)(wsb + (12u << 20));      // 192 KiB
  float* po1 = (float*)(wsb + (12u << 20) + 196608);              // 8 MiB
  float* l0p = (float*)(wsb + (12u << 20) + 196608 + (8u << 20)); // 128 KiB
  float* l1p = l0p + 32768;                                       // 128 KiB

  prep_w<<<384, 256, 0, stream>>>(Wq, Wk, Wv, wt);
  proj_kernel<<<dim3(256, 3), 256, 0, stream>>>(q, k, v, wt, mask, bq, bk, bv, qh, kh, vt);
  attn_kernel<<<dim3(32, 8, 2), 256, 0, stream>>>(qh, kh, vt, mask,
                                                  (float*)d_out, po1, l0p, l1p);
  combine_kernel<<<2048, 256, 0, stream>>>((float*)d_out, po1, l0p, l1p);
}

// Round 6
// 111.177 us; speedup vs baseline: 1.5587x; 1.0059x over previous
//
#include <hip/hip_runtime.h>

typedef __attribute__((ext_vector_type(8))) short bf16x8;
typedef __attribute__((ext_vector_type(4))) float f32x4;
typedef __attribute__((ext_vector_type(4))) unsigned short u16x4;

__device__ __forceinline__ short f2bf(float f) {
  unsigned int u = __builtin_bit_cast(unsigned int, f);
  u += 0x7fffu + ((u >> 16) & 1u);  // RNE
  return (short)(u >> 16);
}

// ---------------- kernel 1: W^T bf16 prep ----------------
__global__ void prep_w(const float* __restrict__ Wq, const float* __restrict__ Wk,
                       const float* __restrict__ Wv, unsigned short* __restrict__ wt) {
  int idx = blockIdx.x * 256 + threadIdx.x;  // < 3*64*512
  int m = idx >> 15;
  int rem = idx & 32767;
  int n = rem >> 9;
  int k = rem & 511;
  const float* W = (m == 0) ? Wq : ((m == 1) ? Wk : Wv);
  wt[idx] = (unsigned short)f2bf(W[k * 64 + n]);
}

// ---------------- kernel 2: QKV projection (bf16 MFMA, occupancy-tuned) ----
// grid (512, 3), 256 thr, 5 blocks/CU (LDS 5x32KB = 160KB, VGPR capped 102).
// Block computes 64 rows x 64 cols; wave = 16 rows. K=512 flattened to 16
// steps of 32 cols; x loads explicitly 2-deep pipelined, prefetch carries
// across the half-boundary barrier (registers survive barriers).
// mode 0 (Q): output scaled by 0.125*log2(e). mode 2 (V): transposed output
// vt[b][dv][s], masked rows zeroed.
__global__ __launch_bounds__(256, 5) void proj_kernel(
    const float* __restrict__ qx, const float* __restrict__ kx, const float* __restrict__ vx,
    const unsigned short* __restrict__ wt, const int* __restrict__ mask,
    const float* __restrict__ bqp, const float* __restrict__ bkp, const float* __restrict__ bvp,
    unsigned short* __restrict__ qo, unsigned short* __restrict__ ko,
    unsigned short* __restrict__ vo) {
  __shared__ unsigned short lds[64 * 256];  // 32 KB (W^T half; reused as V bounce)
  const int mode = blockIdx.y;
  const float* x = (mode == 0) ? qx : ((mode == 1) ? kx : vx);
  const float* bias = (mode == 0) ? bqp : ((mode == 1) ? bkp : bvp);
  const unsigned short* wtm = wt + mode * (64 * 512);
  const float osc = (mode == 0) ? 0.18033688011112042f : 1.0f;  // 0.125*log2(e)

  const int tid = threadIdx.x;
  const int w = tid >> 6, lane = tid & 63;
  const int g = lane >> 4, ln = lane & 15;
  const int rowbase = blockIdx.x * 64;

  const f32x4 fz = {0.f, 0.f, 0.f, 0.f};
  f32x4 acc[4];
#pragma unroll
  for (int nf = 0; nf < 4; ++nf) acc[nf] = fz;

  // per-thread x pointer: row = rowbase + w*16 + ln, col base = g*8
  const float* xrow = x + (size_t)(rowbase + w * 16 + ln) * 512 + g * 8;

  auto stageW = [&](int half) {
#pragma unroll
    for (int i = 0; i < 8; ++i) {
      int c = tid + i * 256;
      int n = c >> 5, kc = c & 31;
      bf16x8 d = *reinterpret_cast<const bf16x8*>(wtm + n * 512 + half * 256 + kc * 8);
      int bo = (n * 512 + kc * 16) ^ ((n & 7) << 4);
      *reinterpret_cast<bf16x8*>(reinterpret_cast<char*>(lds) + bo) = d;
    }
  };

  stageW(0);
  // prologue x loads (t = 0)
  float4 xa = reinterpret_cast<const float4*>(xrow)[0];
  float4 xb = reinterpret_cast<const float4*>(xrow)[1];
  __syncthreads();

#pragma unroll
  for (int t = 0; t < 16; ++t) {  // col chunk = t*32 floats
    float4 na, nb;
    if (t < 15) {
      const float4* np = reinterpret_cast<const float4*>(xrow + (t + 1) * 32);
      na = np[0];
      nb = np[1];
    }
    if (t == 8) {
      __syncthreads();  // all waves done reading W half 0
      stageW(1);
      __syncthreads();
    }
    bf16x8 af;
    af[0] = f2bf(xa.x); af[1] = f2bf(xa.y); af[2] = f2bf(xa.z); af[3] = f2bf(xa.w);
    af[4] = f2bf(xb.x); af[5] = f2bf(xb.y); af[6] = f2bf(xb.z); af[7] = f2bf(xb.w);
    int ks = t & 7;
#pragma unroll
    for (int nf = 0; nf < 4; ++nf) {
      int n = nf * 16 + ln;
      int bo = (n * 512 + ks * 64 + g * 16) ^ ((n & 7) << 4);
      bf16x8 bfrag = *reinterpret_cast<const bf16x8*>(reinterpret_cast<const char*>(lds) + bo);
      acc[nf] = __builtin_amdgcn_mfma_f32_16x16x32_bf16(af, bfrag, acc[nf], 0, 0, 0);
    }
    xa = na;
    xb = nb;
  }

  float bc[4];
#pragma unroll
  for (int nf = 0; nf < 4; ++nf) bc[nf] = bias[nf * 16 + ln];

  if (mode < 2) {
    unsigned short* o = (mode == 0) ? qo : ko;
#pragma unroll
    for (int nf = 0; nf < 4; ++nf)
#pragma unroll
      for (int r = 0; r < 4; ++r) {
        int row = rowbase + w * 16 + g * 4 + r;
        o[(size_t)row * 64 + nf * 16 + ln] = (unsigned short)f2bf((acc[nf][r] + bc[nf]) * osc);
      }
  } else {
    // V: bounce through LDS, emit transposed vt[b][dv][s], zero masked rows
    __syncthreads();
#pragma unroll
    for (int nf = 0; nf < 4; ++nf)
#pragma unroll
      for (int r = 0; r < 4; ++r) {
        int srow = w * 16 + g * 4 + r;
        lds[srow * 64 + nf * 16 + ln] = (unsigned short)f2bf(acc[nf][r] + bc[nf]);
      }
    __syncthreads();
    int b = rowbase >> 12, s0 = rowbase & 4095;
    int dv = tid & 63, sc = tid >> 6;  // sc in 0..3, 16 s-values each
#pragma unroll
    for (int i = 0; i < 2; ++i) {
      int sbase = s0 + sc * 16 + i * 8;
      const int* mrow = mask + b * 4096 + sbase;
      bf16x8 pack;
#pragma unroll
      for (int j = 0; j < 8; ++j) {
        short vvv = (short)lds[(sc * 16 + i * 8 + j) * 64 + dv];
        pack[j] = mrow[j] ? vvv : (short)0;
      }
      *reinterpret_cast<bf16x8*>(vo + (size_t)(b * 64 + dv) * 4096 + sbase) = pack;
    }
  }
}

// ---------------- kernel 3: flash attention (KV-split partials) ----------------
// grid (32, 8, 2), 256 thr (4 waves). Wave owns 32 q-rows (2 B-frags).
// blockIdx.z selects KV half; partial O (raw sums) and partial l written out;
// combine_kernel merges. No-max softmax makes partials purely additive.
#define KVBLK 128
#define NT 16

__global__ __launch_bounds__(256, 2) void attn_kernel(
    const unsigned short* __restrict__ qh, const unsigned short* __restrict__ kh,
    const unsigned short* __restrict__ vt, const int* __restrict__ mask,
    float* __restrict__ out0, float* __restrict__ out1,
    float* __restrict__ l0p, float* __restrict__ l1p) {
  __shared__ unsigned short kt[2][KVBLK * 64];  // 16 KB each, [kv][dk] swizzled
  __shared__ unsigned short vv[2][80 * 128];    // 20 KB each, 256B rows

  const int b = blockIdx.y;
  const int z = blockIdx.z;
  const int kv0 = z * (NT * KVBLK);
  float* __restrict__ optr = z ? out1 : out0;
  float* __restrict__ lptr = z ? l1p : l0p;
  const int qbase = blockIdx.x * 128;
  const int tid = threadIdx.x;
  const int w = tid >> 6, lane = tid & 63;
  const int g = lane >> 4, ln = lane & 15;

  // zero junk rows 65..79 of both vv buffers (read by the l-fragment MFMA)
  for (int i = tid; i < 15 * 128; i += 256) {
    vv[0][65 * 128 + i] = 0;
    vv[1][65 * 128 + i] = 0;
  }

  // Q B-frags (col = ln = q-row, k = 8g+j); qh pre-scaled by 0.125*log2e
  bf16x8 qa[2][2];
#pragma unroll
  for (int qf = 0; qf < 2; ++qf) {
    int row = qbase + w * 32 + qf * 16 + ln;
    const unsigned short* qp = qh + (size_t)(b * 4096 + row) * 64;
    qa[qf][0] = *reinterpret_cast<const bf16x8*>(qp + g * 8);
    qa[qf][1] = *reinterpret_cast<const bf16x8*>(qp + 32 + g * 8);
  }

  const f32x4 fz = {0.f, 0.f, 0.f, 0.f};
  f32x4 accO[2][5];
#pragma unroll
  for (int qf = 0; qf < 2; ++qf)
#pragma unroll
    for (int nf = 0; nf < 5; ++nf) accO[qf][nf] = fz;

  const unsigned short* khb = kh + (size_t)b * 4096 * 64;
  const unsigned short* vtb = vt + (size_t)b * 64 * 4096;

  // ---- staging (register prefetch -> swizzled LDS) ----
  bf16x8 kreg[4], vreg[4];
  int mreg = 0;
  auto issue = [&](int ti) {
    int kvbase = kv0 + ti * KVBLK;
#pragma unroll
    for (int i = 0; i < 4; ++i) {
      int c = tid + i * 256;  // V: dv = c>>4, phys kv start (c&15)*8
      vreg[i] = *reinterpret_cast<const bf16x8*>(vtb + (size_t)(c >> 4) * 4096 + kvbase + (c & 15) * 8);
      // K: row = c>>3 (kv), col16 = c&7
      kreg[i] = *reinterpret_cast<const bf16x8*>(khb + (size_t)(kvbase + (c >> 3)) * 64 + (c & 7) * 8);
    }
    if (tid < KVBLK) mreg = mask[b * 4096 + kvbase + tid];
  };
  auto commit = [&](int bs) {
#pragma unroll
    for (int i = 0; i < 4; ++i) {
      int c = tid + i * 256;
      // K swizzled store
      int kbo = ((c >> 3) * 128 + (c & 7) * 16) ^ (((c >> 3) & 7) << 4);
      *reinterpret_cast<bf16x8*>(reinterpret_cast<char*>(kt[bs]) + kbo) = kreg[i];
      // V tau-permuted store (two 8B halves)
      int dv = c >> 4;
      int P0 = (c & 15) * 8;
      int c2 = P0 >> 5, h = (P0 >> 4) & 1, gg = (P0 >> 2) & 3;
      int x1 = 32 * c2 + 8 * gg + 4 * h;
      int swz = (dv & 7) << 4;
      union { bf16x8 v; u16x4 h4[2]; } sp; sp.v = vreg[i];
      *reinterpret_cast<u16x4*>(reinterpret_cast<char*>(vv[bs]) + ((dv * 256 + 2 * x1) ^ swz)) = sp.h4[0];
      *reinterpret_cast<u16x4*>(reinterpret_cast<char*>(vv[bs]) + ((dv * 256 + 2 * x1 + 16) ^ swz)) = sp.h4[1];
    }
    if (tid < KVBLK) {
      int p = tid;
      int x = 32 * (p >> 5) + 8 * ((p >> 2) & 3) + 4 * ((p >> 4) & 1) + (p & 3);
      vv[bs][64 * 128 + x] = mreg ? (unsigned short)0x3F80 : (unsigned short)0;
    }
  };

  // ---- prologue ----
  issue(0);
  commit(0);
  __syncthreads();
  int cur = 0;

  for (int ti = 0; ti < NT; ++ti) {
    if (ti + 1 < NT) issue(ti + 1);  // loads in flight across compute

    // QK^T swapped: s{qf}[nf][r] = S[kv = nf*16+4g+r][q = qf*16+ln]
    f32x4 s0[8], s1[8];
#pragma unroll
    for (int nf = 0; nf < 8; ++nf) { s0[nf] = fz; s1[nf] = fz; }
    __builtin_amdgcn_s_setprio(1);
#pragma unroll
    for (int c2 = 0; c2 < 2; ++c2)
#pragma unroll
      for (int nf = 0; nf < 8; ++nf) {
        int kvr = nf * 16 + ln;
        int bo = (kvr * 128 + c2 * 64 + g * 16) ^ ((kvr & 7) << 4);
        bf16x8 kf = *reinterpret_cast<const bf16x8*>(reinterpret_cast<const char*>(kt[cur]) + bo);
        s0[nf] = __builtin_amdgcn_mfma_f32_16x16x32_bf16(kf, qa[0][c2], s0[nf], 0, 0, 0);
        s1[nf] = __builtin_amdgcn_mfma_f32_16x16x32_bf16(kf, qa[1][c2], s1[nf], 0, 0, 0);
      }
    __builtin_amdgcn_s_setprio(0);

    // p = exp2(s); pack to PV A-frag words (zero cross-lane via tau)
    unsigned int pw[2][4][4];
#pragma unroll
    for (int c2 = 0; c2 < 4; ++c2)
#pragma unroll
      for (int hh = 0; hh < 2; ++hh) {
        {
          float p0 = __builtin_exp2f(s0[2 * c2 + hh][0]);
          float p1 = __builtin_exp2f(s0[2 * c2 + hh][1]);
          float p2 = __builtin_exp2f(s0[2 * c2 + hh][2]);
          float p3 = __builtin_exp2f(s0[2 * c2 + hh][3]);
          unsigned int w0, w1;
          asm("v_cvt_pk_bf16_f32 %0, %1, %2" : "=v"(w0) : "v"(p0), "v"(p1));
          asm("v_cvt_pk_bf16_f32 %0, %1, %2" : "=v"(w1) : "v"(p2), "v"(p3));
          pw[0][c2][2 * hh] = w0;
          pw[0][c2][2 * hh + 1] = w1;
        }
        {
          float p0 = __builtin_exp2f(s1[2 * c2 + hh][0]);
          float p1 = __builtin_exp2f(s1[2 * c2 + hh][1]);
          float p2 = __builtin_exp2f(s1[2 * c2 + hh][2]);
          float p3 = __builtin_exp2f(s1[2 * c2 + hh][3]);
          unsigned int w0, w1;
          asm("v_cvt_pk_bf16_f32 %0, %1, %2" : "=v"(w0) : "v"(p0), "v"(p1));
          asm("v_cvt_pk_bf16_f32 %0, %1, %2" : "=v"(w1) : "v"(p2), "v"(p3));
          pw[1][c2][2 * hh] = w0;
          pw[1][c2][2 * hh + 1] = w1;
        }
      }

    // PV: O'[q][dv] += P·V  (A = in-reg P, B = vv frags; nf==4 -> l column)
    __builtin_amdgcn_s_setprio(1);
#pragma unroll
    for (int c2 = 0; c2 < 4; ++c2) {
      union { unsigned int u[4]; bf16x8 v; } pa0, pa1;
#pragma unroll
      for (int t = 0; t < 4; ++t) { pa0.u[t] = pw[0][c2][t]; pa1.u[t] = pw[1][c2][t]; }
#pragma unroll
      for (int nf = 0; nf < 5; ++nf) {
        int dvr = nf * 16 + ln;
        int bo = (dvr * 256 + c2 * 64 + g * 16) ^ ((dvr & 7) << 4);
        bf16x8 vb = *reinterpret_cast<const bf16x8*>(reinterpret_cast<const char*>(vv[cur]) + bo);
        accO[0][nf] = __builtin_amdgcn_mfma_f32_16x16x32_bf16(pa0.v, vb, accO[0][nf], 0, 0, 0);
        accO[1][nf] = __builtin_amdgcn_mfma_f32_16x16x32_bf16(pa1.v, vb, accO[1][nf], 0, 0, 0);
      }
    }
    __builtin_amdgcn_s_setprio(0);

    if (ti + 1 < NT) commit(cur ^ 1);
    __syncthreads();
    cur ^= 1;
  }

  // epilogue: raw partial O; l-frag valid at ln==0 lanes (dvr=64 column)
#pragma unroll
  for (int qf = 0; qf < 2; ++qf)
#pragma unroll
    for (int r = 0; r < 4; ++r) {
      int grow = b * 4096 + qbase + w * 32 + qf * 16 + g * 4 + r;
#pragma unroll
      for (int nf = 0; nf < 4; ++nf)
        optr[(size_t)grow * 64 + nf * 16 + ln] = accO[qf][nf][r];
      if (ln == 0) lptr[grow] = accO[qf][4][r];
    }
}

// ---------------- kernel 4: combine partials ----------------
// out = (O0 + O1) / (l0 + l1); 524288 float4s, grid 2048 x 256
__global__ __launch_bounds__(256) void combine_kernel(
    float* __restrict__ out, const float* __restrict__ po1,
    const float* __restrict__ l0p, const float* __restrict__ l1p) {
  int idx = blockIdx.x * 256 + threadIdx.x;
  int row = idx >> 4;  // 16 float4 per 64-col row
  float rl = 1.0f / (l0p[row] + l1p[row]);
  float4 a = reinterpret_cast<float4*>(out)[idx];
  float4 c = reinterpret_cast<const float4*>(po1)[idx];
  a.x = (a.x + c.x) * rl;
  a.y = (a.y + c.y) * rl;
  a.z = (a.z + c.z) * rl;
  a.w = (a.w + c.w) * rl;
  reinterpret_cast<float4*>(out)[idx] = a;
}

extern "C" void kernel_launch(void* const* d_in, const int* in_sizes, int n_in,
                              void* d_out, int out_size, void* d_ws, size_t ws_size,
                              hipStream_t stream) {
  const float* q = (const float*)d_in[0];
  const float* k = (const float*)d_in[1];
  const float* v = (const float*)d_in[2];
  const int* mask = (const int*)d_in[3];
  const float* Wq = (const float*)d_in[4];
  const float* bq = (const float*)d_in[5];
  const float* Wk = (const float*)d_in[6];
  const float* bk = (const float*)d_in[7];
  const float* Wv = (const float*)d_in[8];
  const float* bv = (const float*)d_in[9];

  char* wsb = (char*)d_ws;
  unsigned short* qh = (unsigned short*)(wsb);                    // 4 MiB
  unsigned short* kh = (unsigned short*)(wsb + (4u << 20));       // 4 MiB
  unsigned short* vt = (unsigned short*)(wsb + (8u << 20));       // 4 MiB
  unsigned short* wt = (unsigned short*)(wsb + (12u << 20));      // 192 KiB
  float* po1 = (float*)(wsb + (12u << 20) + 196608);              // 8 MiB
  float* l0p = (float*)(wsb + (12u << 20) + 196608 + (8u << 20)); // 128 KiB
  float* l1p = l0p + 32768;                                       // 128 KiB

  prep_w<<<384, 256, 0, stream>>>(Wq, Wk, Wv, wt);
  proj_kernel<<<dim3(512, 3), 256, 0, stream>>>(q, k, v, wt, mask, bq, bk, bv, qh, kh, vt);
  attn_kernel<<<dim3(32, 8, 2), 256, 0, stream>>>(qh, kh, vt, mask,
                                                  (float*)d_out, po1, l0p, l1p);
  combine_kernel<<<2048, 256, 0, stream>>>((float*)d_out, po1, l0p, l1p);
}

// Round 7
// 109.780 us; speedup vs baseline: 1.5785x; 1.0127x over previous
//
#include <hip/hip_runtime.h>

typedef __attribute__((ext_vector_type(8))) short bf16x8;
typedef __attribute__((ext_vector_type(4))) float f32x4;
typedef __attribute__((ext_vector_type(4))) unsigned short u16x4;

__device__ __forceinline__ short f2bf(float f) {
  unsigned int u = __builtin_bit_cast(unsigned int, f);
  u += 0x7fffu + ((u >> 16) & 1u);  // RNE
  return (short)(u >> 16);
}

// ---------------- kernel 1: W^T bf16 prep ----------------
__global__ void prep_w(const float* __restrict__ Wq, const float* __restrict__ Wk,
                       const float* __restrict__ Wv, unsigned short* __restrict__ wt) {
  int idx = blockIdx.x * 256 + threadIdx.x;  // < 3*64*512
  int m = idx >> 15;
  int rem = idx & 32767;
  int n = rem >> 9;
  int k = rem & 511;
  const float* W = (m == 0) ? Wq : ((m == 1) ? Wk : Wv);
  wt[idx] = (unsigned short)f2bf(W[k * 64 + n]);
}

// ---------------- kernel 2: QKV projection (row-contiguous staging) ----------
// grid (1024, 3), 256 thr (4 waves), 2 blocks/CU (LDS 64 KB).
// Block = 32 rows x 64 outcols, full K=512. Stage: 64 KB of x read as fully
// CONTIGUOUS float4 streams (1 KB/wave-instruction), converted to bf16,
// XOR-swizzled into LDS. Fixes the 128B-per-2KB-stride DRAM pattern that
// pinned prior versions at ~2.3 TB/s.
// Wave: rows (w&1)*16..+15, outcols (w>>1)*32..+31.
// mode 0 (Q): scaled by 0.125*log2(e). mode 2 (V): transposed vt[b][dv][s],
// masked rows zeroed.
__global__ __launch_bounds__(256, 2) void proj_kernel(
    const float* __restrict__ qx, const float* __restrict__ kx, const float* __restrict__ vx,
    const unsigned short* __restrict__ wt, const int* __restrict__ mask,
    const float* __restrict__ bqp, const float* __restrict__ bkp, const float* __restrict__ bvp,
    unsigned short* __restrict__ qo, unsigned short* __restrict__ ko,
    unsigned short* __restrict__ vo) {
  __shared__ unsigned short xs[32 * 512];  // 32 KB x-tile bf16, swizzled; reused as V bounce
  __shared__ unsigned short wl[64 * 256];  // 32 KB W^T half, swizzled

  const int mode = blockIdx.y;
  const float* x = (mode == 0) ? qx : ((mode == 1) ? kx : vx);
  const float* bias = (mode == 0) ? bqp : ((mode == 1) ? bkp : bvp);
  const unsigned short* wtm = wt + mode * (64 * 512);
  const float osc = (mode == 0) ? 0.18033688011112042f : 1.0f;  // 0.125*log2(e)

  const int tid = threadIdx.x;
  const int w = tid >> 6, lane = tid & 63;
  const int g = lane >> 4, ln = lane & 15;
  const int rowbase = blockIdx.x * 32;
  const int rh = w & 1, h = w >> 1;  // row-half, outcol-half

  auto stageW = [&](int half) {
#pragma unroll
    for (int i = 0; i < 8; ++i) {
      int c = tid + i * 256;
      int n = c >> 5, kc = c & 31;
      bf16x8 d = *reinterpret_cast<const bf16x8*>(wtm + n * 512 + half * 256 + kc * 8);
      int bo = (n * 512 + kc * 16) ^ ((n & 7) << 4);
      *reinterpret_cast<bf16x8*>(reinterpret_cast<char*>(wl) + bo) = d;
    }
  };

  // stage x: 32 rows x 512 cols fp32 -> bf16 LDS, fully linear global reads
  {
    const float* src = x + (size_t)rowbase * 512;
#pragma unroll
    for (int i = 0; i < 16; ++i) {
      int idx = i * 256 + tid;  // f4-unit index, 0..4095 (128 per row)
      float4 d = *reinterpret_cast<const float4*>(src + (size_t)idx * 4);
      int row = idx >> 7, col4 = idx & 127;
      u16x4 pk;
      pk[0] = (unsigned short)f2bf(d.x);
      pk[1] = (unsigned short)f2bf(d.y);
      pk[2] = (unsigned short)f2bf(d.z);
      pk[3] = (unsigned short)f2bf(d.w);
      int u8 = col4 ^ ((row & 7) << 1);
      *reinterpret_cast<u16x4*>(reinterpret_cast<char*>(xs) + row * 1024 + u8 * 8) = pk;
    }
  }
  stageW(0);
  __syncthreads();

  const f32x4 fz = {0.f, 0.f, 0.f, 0.f};
  f32x4 acc[2];
  acc[0] = fz;
  acc[1] = fz;

  const int lrow = rh * 16 + ln;
  const char* xrow_lds = reinterpret_cast<const char*>(xs) + lrow * 1024;
  const int c7 = lrow & 7;

#pragma unroll
  for (int t = 0; t < 16; ++t) {
    if (t == 8) {
      __syncthreads();  // all waves done with W half 0
      stageW(1);
      __syncthreads();
    }
    int v = t * 4 + g;  // 16B unit within row
    bf16x8 af = *reinterpret_cast<const bf16x8*>(xrow_lds + ((v ^ c7) * 16));
    int ks = t & 7;
#pragma unroll
    for (int nfi = 0; nfi < 2; ++nfi) {
      int n = h * 32 + nfi * 16 + ln;
      int bo = (n * 512 + ks * 64 + g * 16) ^ ((n & 7) << 4);
      bf16x8 bfrag = *reinterpret_cast<const bf16x8*>(reinterpret_cast<const char*>(wl) + bo);
      acc[nfi] = __builtin_amdgcn_mfma_f32_16x16x32_bf16(af, bfrag, acc[nfi], 0, 0, 0);
    }
  }

  float bc[2];
#pragma unroll
  for (int nfi = 0; nfi < 2; ++nfi) bc[nfi] = bias[h * 32 + nfi * 16 + ln];

  if (mode < 2) {
    unsigned short* o = (mode == 0) ? qo : ko;
#pragma unroll
    for (int nfi = 0; nfi < 2; ++nfi)
#pragma unroll
      for (int r = 0; r < 4; ++r) {
        int row = rowbase + rh * 16 + g * 4 + r;
        o[(size_t)row * 64 + h * 32 + nfi * 16 + ln] =
            (unsigned short)f2bf((acc[nfi][r] + bc[nfi]) * osc);
      }
  } else {
    // V: bounce through xs (done reading it), emit vt[b][dv][s], mask-zeroed
    __syncthreads();
#pragma unroll
    for (int nfi = 0; nfi < 2; ++nfi)
#pragma unroll
      for (int r = 0; r < 4; ++r) {
        int srow = rh * 16 + g * 4 + r;
        xs[srow * 64 + h * 32 + nfi * 16 + ln] = (unsigned short)f2bf(acc[nfi][r] + bc[nfi]);
      }
    __syncthreads();
    int b = rowbase >> 12, s0 = rowbase & 4095;
    int dv = tid & 63, sc = tid >> 6;  // sc 0..3, 8 s each
    int sbase = s0 + sc * 8;
    const int* mrow = mask + b * 4096 + sbase;
    bf16x8 pack;
#pragma unroll
    for (int j = 0; j < 8; ++j) {
      short vvv = (short)xs[(sc * 8 + j) * 64 + dv];
      pack[j] = mrow[j] ? vvv : (short)0;
    }
    *reinterpret_cast<bf16x8*>(vo + (size_t)(b * 64 + dv) * 4096 + sbase) = pack;
  }
}

// ---------------- kernel 3: flash attention (KV-split partials) ----------------
// grid (32, 8, 2), 256 thr (4 waves). Wave owns 32 q-rows (2 B-frags).
// blockIdx.z selects KV half; partial O (raw sums) and partial l written out;
// combine_kernel merges. No-max softmax makes partials purely additive.
#define KVBLK 128
#define NT 16

__global__ __launch_bounds__(256, 2) void attn_kernel(
    const unsigned short* __restrict__ qh, const unsigned short* __restrict__ kh,
    const unsigned short* __restrict__ vt, const int* __restrict__ mask,
    float* __restrict__ out0, float* __restrict__ out1,
    float* __restrict__ l0p, float* __restrict__ l1p) {
  __shared__ unsigned short kt[2][KVBLK * 64];  // 16 KB each, [kv][dk] swizzled
  __shared__ unsigned short vv[2][80 * 128];    // 20 KB each, 256B rows

  const int b = blockIdx.y;
  const int z = blockIdx.z;
  const int kv0 = z * (NT * KVBLK);
  float* __restrict__ optr = z ? out1 : out0;
  float* __restrict__ lptr = z ? l1p : l0p;
  const int qbase = blockIdx.x * 128;
  const int tid = threadIdx.x;
  const int w = tid >> 6, lane = tid & 63;
  const int g = lane >> 4, ln = lane & 15;

  // zero junk rows 65..79 of both vv buffers (read by the l-fragment MFMA)
  for (int i = tid; i < 15 * 128; i += 256) {
    vv[0][65 * 128 + i] = 0;
    vv[1][65 * 128 + i] = 0;
  }

  // Q B-frags (col = ln = q-row, k = 8g+j); qh pre-scaled by 0.125*log2e
  bf16x8 qa[2][2];
#pragma unroll
  for (int qf = 0; qf < 2; ++qf) {
    int row = qbase + w * 32 + qf * 16 + ln;
    const unsigned short* qp = qh + (size_t)(b * 4096 + row) * 64;
    qa[qf][0] = *reinterpret_cast<const bf16x8*>(qp + g * 8);
    qa[qf][1] = *reinterpret_cast<const bf16x8*>(qp + 32 + g * 8);
  }

  const f32x4 fz = {0.f, 0.f, 0.f, 0.f};
  f32x4 accO[2][5];
#pragma unroll
  for (int qf = 0; qf < 2; ++qf)
#pragma unroll
    for (int nf = 0; nf < 5; ++nf) accO[qf][nf] = fz;

  const unsigned short* khb = kh + (size_t)b * 4096 * 64;
  const unsigned short* vtb = vt + (size_t)b * 64 * 4096;

  // ---- staging (register prefetch -> swizzled LDS) ----
  bf16x8 kreg[4], vreg[4];
  int mreg = 0;
  auto issue = [&](int ti) {
    int kvbase = kv0 + ti * KVBLK;
#pragma unroll
    for (int i = 0; i < 4; ++i) {
      int c = tid + i * 256;  // V: dv = c>>4, phys kv start (c&15)*8
      vreg[i] = *reinterpret_cast<const bf16x8*>(vtb + (size_t)(c >> 4) * 4096 + kvbase + (c & 15) * 8);
      // K: row = c>>3 (kv), col16 = c&7
      kreg[i] = *reinterpret_cast<const bf16x8*>(khb + (size_t)(kvbase + (c >> 3)) * 64 + (c & 7) * 8);
    }
    if (tid < KVBLK) mreg = mask[b * 4096 + kvbase + tid];
  };
  auto commit = [&](int bs) {
#pragma unroll
    for (int i = 0; i < 4; ++i) {
      int c = tid + i * 256;
      // K swizzled store
      int kbo = ((c >> 3) * 128 + (c & 7) * 16) ^ (((c >> 3) & 7) << 4);
      *reinterpret_cast<bf16x8*>(reinterpret_cast<char*>(kt[bs]) + kbo) = kreg[i];
      // V tau-permuted store (two 8B halves)
      int dv = c >> 4;
      int P0 = (c & 15) * 8;
      int c2 = P0 >> 5, hh = (P0 >> 4) & 1, gg = (P0 >> 2) & 3;
      int x1 = 32 * c2 + 8 * gg + 4 * hh;
      int swz = (dv & 7) << 4;
      union { bf16x8 v; u16x4 h4[2]; } sp; sp.v = vreg[i];
      *reinterpret_cast<u16x4*>(reinterpret_cast<char*>(vv[bs]) + ((dv * 256 + 2 * x1) ^ swz)) = sp.h4[0];
      *reinterpret_cast<u16x4*>(reinterpret_cast<char*>(vv[bs]) + ((dv * 256 + 2 * x1 + 16) ^ swz)) = sp.h4[1];
    }
    if (tid < KVBLK) {
      int p = tid;
      int xx = 32 * (p >> 5) + 8 * ((p >> 2) & 3) + 4 * ((p >> 4) & 1) + (p & 3);
      vv[bs][64 * 128 + xx] = mreg ? (unsigned short)0x3F80 : (unsigned short)0;
    }
  };

  // ---- prologue ----
  issue(0);
  commit(0);
  __syncthreads();
  int cur = 0;

  for (int ti = 0; ti < NT; ++ti) {
    if (ti + 1 < NT) issue(ti + 1);  // loads in flight across compute

    // QK^T swapped: s{qf}[nf][r] = S[kv = nf*16+4g+r][q = qf*16+ln]
    f32x4 s0[8], s1[8];
#pragma unroll
    for (int nf = 0; nf < 8; ++nf) { s0[nf] = fz; s1[nf] = fz; }
    __builtin_amdgcn_s_setprio(1);
#pragma unroll
    for (int c2 = 0; c2 < 2; ++c2)
#pragma unroll
      for (int nf = 0; nf < 8; ++nf) {
        int kvr = nf * 16 + ln;
        int bo = (kvr * 128 + c2 * 64 + g * 16) ^ ((kvr & 7) << 4);
        bf16x8 kf = *reinterpret_cast<const bf16x8*>(reinterpret_cast<const char*>(kt[cur]) + bo);
        s0[nf] = __builtin_amdgcn_mfma_f32_16x16x32_bf16(kf, qa[0][c2], s0[nf], 0, 0, 0);
        s1[nf] = __builtin_amdgcn_mfma_f32_16x16x32_bf16(kf, qa[1][c2], s1[nf], 0, 0, 0);
      }
    __builtin_amdgcn_s_setprio(0);

    // p = exp2(s); pack to PV A-frag words (zero cross-lane via tau)
    unsigned int pw[2][4][4];
#pragma unroll
    for (int c2 = 0; c2 < 4; ++c2)
#pragma unroll
      for (int hh = 0; hh < 2; ++hh) {
        {
          float p0 = __builtin_exp2f(s0[2 * c2 + hh][0]);
          float p1 = __builtin_exp2f(s0[2 * c2 + hh][1]);
          float p2 = __builtin_exp2f(s0[2 * c2 + hh][2]);
          float p3 = __builtin_exp2f(s0[2 * c2 + hh][3]);
          unsigned int w0, w1;
          asm("v_cvt_pk_bf16_f32 %0, %1, %2" : "=v"(w0) : "v"(p0), "v"(p1));
          asm("v_cvt_pk_bf16_f32 %0, %1, %2" : "=v"(w1) : "v"(p2), "v"(p3));
          pw[0][c2][2 * hh] = w0;
          pw[0][c2][2 * hh + 1] = w1;
        }
        {
          float p0 = __builtin_exp2f(s1[2 * c2 + hh][0]);
          float p1 = __builtin_exp2f(s1[2 * c2 + hh][1]);
          float p2 = __builtin_exp2f(s1[2 * c2 + hh][2]);
          float p3 = __builtin_exp2f(s1[2 * c2 + hh][3]);
          unsigned int w0, w1;
          asm("v_cvt_pk_bf16_f32 %0, %1, %2" : "=v"(w0) : "v"(p0), "v"(p1));
          asm("v_cvt_pk_bf16_f32 %0, %1, %2" : "=v"(w1) : "v"(p2), "v"(p3));
          pw[1][c2][2 * hh] = w0;
          pw[1][c2][2 * hh + 1] = w1;
        }
      }

    // PV: O'[q][dv] += P·V  (A = in-reg P, B = vv frags; nf==4 -> l column)
    __builtin_amdgcn_s_setprio(1);
#pragma unroll
    for (int c2 = 0; c2 < 4; ++c2) {
      union { unsigned int u[4]; bf16x8 v; } pa0, pa1;
#pragma unroll
      for (int t = 0; t < 4; ++t) { pa0.u[t] = pw[0][c2][t]; pa1.u[t] = pw[1][c2][t]; }
#pragma unroll
      for (int nf = 0; nf < 5; ++nf) {
        int dvr = nf * 16 + ln;
        int bo = (dvr * 256 + c2 * 64 + g * 16) ^ ((dvr & 7) << 4);
        bf16x8 vb = *reinterpret_cast<const bf16x8*>(reinterpret_cast<const char*>(vv[cur]) + bo);
        accO[0][nf] = __builtin_amdgcn_mfma_f32_16x16x32_bf16(pa0.v, vb, accO[0][nf], 0, 0, 0);
        accO[1][nf] = __builtin_amdgcn_mfma_f32_16x16x32_bf16(pa1.v, vb, accO[1][nf], 0, 0, 0);
      }
    }
    __builtin_amdgcn_s_setprio(0);

    if (ti + 1 < NT) commit(cur ^ 1);
    __syncthreads();
    cur ^= 1;
  }

  // epilogue: raw partial O; l-frag valid at ln==0 lanes (dvr=64 column)
#pragma unroll
  for (int qf = 0; qf < 2; ++qf)
#pragma unroll
    for (int r = 0; r < 4; ++r) {
      int grow = b * 4096 + qbase + w * 32 + qf * 16 + g * 4 + r;
#pragma unroll
      for (int nf = 0; nf < 4; ++nf)
        optr[(size_t)grow * 64 + nf * 16 + ln] = accO[qf][nf][r];
      if (ln == 0) lptr[grow] = accO[qf][4][r];
    }
}

// ---------------- kernel 4: combine partials ----------------
// out = (O0 + O1) / (l0 + l1); 524288 float4s, grid 2048 x 256
__global__ __launch_bounds__(256) void combine_kernel(
    float* __restrict__ out, const float* __restrict__ po1,
    const float* __restrict__ l0p, const float* __restrict__ l1p) {
  int idx = blockIdx.x * 256 + threadIdx.x;
  int row = idx >> 4;  // 16 float4 per 64-col row
  float rl = 1.0f / (l0p[row] + l1p[row]);
  float4 a = reinterpret_cast<float4*>(out)[idx];
  float4 c = reinterpret_cast<const float4*>(po1)[idx];
  a.x = (a.x + c.x) * rl;
  a.y = (a.y + c.y) * rl;
  a.z = (a.z + c.z) * rl;
  a.w = (a.w + c.w) * rl;
  reinterpret_cast<float4*>(out)[idx] = a;
}

extern "C" void kernel_launch(void* const* d_in, const int* in_sizes, int n_in,
                              void* d_out, int out_size, void* d_ws, size_t ws_size,
                              hipStream_t stream) {
  const float* q = (const float*)d_in[0];
  const float* k = (const float*)d_in[1];
  const float* v = (const float*)d_in[2];
  const int* mask = (const int*)d_in[3];
  const float* Wq = (const float*)d_in[4];
  const float* bq = (const float*)d_in[5];
  const float* Wk = (const float*)d_in[6];
  const float* bk = (const float*)d_in[7];
  const float* Wv = (const float*)d_in[8];
  const float* bv = (const float*)d_in[9];

  char* wsb = (char*)d_ws;
  unsigned short* qh = (unsigned short*)(wsb);                    // 4 MiB
  unsigned short* kh = (unsigned short*)(wsb + (4u << 20));       // 4 MiB
  unsigned short* vt = (unsigned short*)(wsb + (8u << 20));       // 4 MiB
  unsigned short* wt = (unsigned short*)(wsb + (12u << 20));      // 192 KiB
  float* po1 = (float*)(wsb + (12u << 20) + 196608);              // 8 MiB
  float* l0p = (float*)(wsb + (12u << 20) + 196608 + (8u << 20)); // 128 KiB
  float* l1p = l0p + 32768;                                       // 128 KiB

  prep_w<<<384, 256, 0, stream>>>(Wq, Wk, Wv, wt);
  proj_kernel<<<dim3(1024, 3), 256, 0, stream>>>(q, k, v, wt, mask, bq, bk, bv, qh, kh, vt);
  attn_kernel<<<dim3(32, 8, 2), 256, 0, stream>>>(qh, kh, vt, mask,
                                                  (float*)d_out, po1, l0p, l1p);
  combine_kernel<<<2048, 256, 0, stream>>>((float*)d_out, po1, l0p, l1p);
}

// Round 8
// 106.972 us; speedup vs baseline: 1.6200x; 1.0262x over previous
//
#include <hip/hip_runtime.h>

typedef __attribute__((ext_vector_type(8))) short bf16x8;
typedef __attribute__((ext_vector_type(4))) float f32x4;
typedef __attribute__((ext_vector_type(4))) unsigned short u16x4;

__device__ __forceinline__ short f2bf(float f) {
  unsigned int u = __builtin_bit_cast(unsigned int, f);
  u += 0x7fffu + ((u >> 16) & 1u);  // RNE
  return (short)(u >> 16);
}

// ---------------- kernel 1: W^T bf16 prep ----------------
__global__ void prep_w(const float* __restrict__ Wq, const float* __restrict__ Wk,
                       const float* __restrict__ Wv, unsigned short* __restrict__ wt) {
  int idx = blockIdx.x * 256 + threadIdx.x;  // < 3*64*512
  int m = idx >> 15;
  int rem = idx & 32767;
  int n = rem >> 9;
  int k = rem & 511;
  const float* W = (m == 0) ? Wq : ((m == 1) ? Wk : Wv);
  wt[idx] = (unsigned short)f2bf(W[k * 64 + n]);
}

// ---------------- kernel 2: QKV projection (batch-issued staging) ----------
// grid (1024, 3), 256 thr (4 waves), 2 blocks/CU (LDS 64 KB).
// Block = 32 rows x 64 outcols, full K=512. The stage phase BATCH-ISSUES all
// global loads per thread (8 W bf16x8, then 16 x float4) before any consumer,
// so each wave keeps ~16 KB in flight (vs ~2-3 loads with the fused
// load/convert/store loop that pinned effective read BW at 2.5 TB/s).
// W first: its LDS stores then wait only on the L2-fast W loads (FIFO vmcnt).
// mode 0 (Q): scaled by 0.125*log2(e). mode 2 (V): transposed vt[b][dv][s],
// masked rows zeroed.
__global__ __launch_bounds__(256, 2) void proj_kernel(
    const float* __restrict__ qx, const float* __restrict__ kx, const float* __restrict__ vx,
    const unsigned short* __restrict__ wt, const int* __restrict__ mask,
    const float* __restrict__ bqp, const float* __restrict__ bkp, const float* __restrict__ bvp,
    unsigned short* __restrict__ qo, unsigned short* __restrict__ ko,
    unsigned short* __restrict__ vo) {
  __shared__ unsigned short xs[32 * 512];  // 32 KB x-tile bf16, swizzled; reused as V bounce
  __shared__ unsigned short wl[64 * 256];  // 32 KB W^T half, swizzled

  const int mode = blockIdx.y;
  const float* x = (mode == 0) ? qx : ((mode == 1) ? kx : vx);
  const float* bias = (mode == 0) ? bqp : ((mode == 1) ? bkp : bvp);
  const unsigned short* wtm = wt + mode * (64 * 512);
  const float osc = (mode == 0) ? 0.18033688011112042f : 1.0f;  // 0.125*log2(e)

  const int tid = threadIdx.x;
  const int w = tid >> 6, lane = tid & 63;
  const int g = lane >> 4, ln = lane & 15;
  const int rowbase = blockIdx.x * 32;
  const int rh = w & 1, h = w >> 1;  // row-half, outcol-half

  // ---- stage phase: batch-issue all loads, then consume ----
  {
    // (1) issue W half-0 loads (L2-fast)
    bf16x8 wreg[8];
#pragma unroll
    for (int i = 0; i < 8; ++i) {
      int c = tid + i * 256;
      int n = c >> 5, kc = c & 31;
      wreg[i] = *reinterpret_cast<const bf16x8*>(wtm + n * 512 + kc * 8);
    }
    // (2) issue all 16 x float4 loads (HBM, long latency)
    const float* src = x + (size_t)rowbase * 512;
    float4 xr[16];
#pragma unroll
    for (int i = 0; i < 16; ++i) {
      int idx = i * 256 + tid;  // f4-unit index, 0..4095 (128 per row)
      xr[i] = *reinterpret_cast<const float4*>(src + (size_t)idx * 4);
    }
    // (3) store W half-0 (waits only on W loads)
#pragma unroll
    for (int i = 0; i < 8; ++i) {
      int c = tid + i * 256;
      int n = c >> 5, kc = c & 31;
      int bo = (n * 512 + kc * 16) ^ ((n & 7) << 4);
      *reinterpret_cast<bf16x8*>(reinterpret_cast<char*>(wl) + bo) = wreg[i];
    }
    // (4) convert + store x (waits on x loads)
#pragma unroll
    for (int i = 0; i < 16; ++i) {
      int idx = i * 256 + tid;
      int row = idx >> 7, col4 = idx & 127;
      unsigned int pk0, pk1;
      asm("v_cvt_pk_bf16_f32 %0, %1, %2" : "=v"(pk0) : "v"(xr[i].x), "v"(xr[i].y));
      asm("v_cvt_pk_bf16_f32 %0, %1, %2" : "=v"(pk1) : "v"(xr[i].z), "v"(xr[i].w));
      union { unsigned int u[2]; u16x4 v; } pk;
      pk.u[0] = pk0;
      pk.u[1] = pk1;
      int u8 = col4 ^ ((row & 7) << 1);
      *reinterpret_cast<u16x4*>(reinterpret_cast<char*>(xs) + row * 1024 + u8 * 8) = pk.v;
    }
  }
  __syncthreads();

  const f32x4 fz = {0.f, 0.f, 0.f, 0.f};
  f32x4 acc[2];
  acc[0] = fz;
  acc[1] = fz;

  const int lrow = rh * 16 + ln;
  const char* xrow_lds = reinterpret_cast<const char*>(xs) + lrow * 1024;
  const int c7 = lrow & 7;

#pragma unroll
  for (int t = 0; t < 16; ++t) {
    if (t == 8) {
      __syncthreads();  // all waves done with W half 0
      // restage W half 1 (batch-issue then store)
      bf16x8 wreg[8];
#pragma unroll
      for (int i = 0; i < 8; ++i) {
        int c = tid + i * 256;
        int n = c >> 5, kc = c & 31;
        wreg[i] = *reinterpret_cast<const bf16x8*>(wtm + n * 512 + 256 + kc * 8);
      }
#pragma unroll
      for (int i = 0; i < 8; ++i) {
        int c = tid + i * 256;
        int n = c >> 5, kc = c & 31;
        int bo = (n * 512 + kc * 16) ^ ((n & 7) << 4);
        *reinterpret_cast<bf16x8*>(reinterpret_cast<char*>(wl) + bo) = wreg[i];
      }
      __syncthreads();
    }
    int v = t * 4 + g;  // 16B unit within row
    bf16x8 af = *reinterpret_cast<const bf16x8*>(xrow_lds + ((v ^ c7) * 16));
    int ks = t & 7;
#pragma unroll
    for (int nfi = 0; nfi < 2; ++nfi) {
      int n = h * 32 + nfi * 16 + ln;
      int bo = (n * 512 + ks * 64 + g * 16) ^ ((n & 7) << 4);
      bf16x8 bfrag = *reinterpret_cast<const bf16x8*>(reinterpret_cast<const char*>(wl) + bo);
      acc[nfi] = __builtin_amdgcn_mfma_f32_16x16x32_bf16(af, bfrag, acc[nfi], 0, 0, 0);
    }
  }

  float bc[2];
#pragma unroll
  for (int nfi = 0; nfi < 2; ++nfi) bc[nfi] = bias[h * 32 + nfi * 16 + ln];

  if (mode < 2) {
    unsigned short* o = (mode == 0) ? qo : ko;
#pragma unroll
    for (int nfi = 0; nfi < 2; ++nfi)
#pragma unroll
      for (int r = 0; r < 4; ++r) {
        int row = rowbase + rh * 16 + g * 4 + r;
        o[(size_t)row * 64 + h * 32 + nfi * 16 + ln] =
            (unsigned short)f2bf((acc[nfi][r] + bc[nfi]) * osc);
      }
  } else {
    // V: bounce through xs (done reading it), emit vt[b][dv][s], mask-zeroed
    __syncthreads();
#pragma unroll
    for (int nfi = 0; nfi < 2; ++nfi)
#pragma unroll
      for (int r = 0; r < 4; ++r) {
        int srow = rh * 16 + g * 4 + r;
        xs[srow * 64 + h * 32 + nfi * 16 + ln] = (unsigned short)f2bf(acc[nfi][r] + bc[nfi]);
      }
    __syncthreads();
    int b = rowbase >> 12, s0 = rowbase & 4095;
    int dv = tid & 63, sc = tid >> 6;  // sc 0..3, 8 s each
    int sbase = s0 + sc * 8;
    const int* mrow = mask + b * 4096 + sbase;
    bf16x8 pack;
#pragma unroll
    for (int j = 0; j < 8; ++j) {
      short vvv = (short)xs[(sc * 8 + j) * 64 + dv];
      pack[j] = mrow[j] ? vvv : (short)0;
    }
    *reinterpret_cast<bf16x8*>(vo + (size_t)(b * 64 + dv) * 4096 + sbase) = pack;
  }
}

// ---------------- kernel 3: flash attention (KV-split partials) ----------------
// grid (32, 8, 2), 256 thr (4 waves). Wave owns 32 q-rows (2 B-frags).
// blockIdx.z selects KV half; partial O (raw sums) and partial l written out;
// combine_kernel merges. No-max softmax makes partials purely additive.
#define KVBLK 128
#define NT 16

__global__ __launch_bounds__(256, 2) void attn_kernel(
    const unsigned short* __restrict__ qh, const unsigned short* __restrict__ kh,
    const unsigned short* __restrict__ vt, const int* __restrict__ mask,
    float* __restrict__ out0, float* __restrict__ out1,
    float* __restrict__ l0p, float* __restrict__ l1p) {
  __shared__ unsigned short kt[2][KVBLK * 64];  // 16 KB each, [kv][dk] swizzled
  __shared__ unsigned short vv[2][80 * 128];    // 20 KB each, 256B rows

  const int b = blockIdx.y;
  const int z = blockIdx.z;
  const int kv0 = z * (NT * KVBLK);
  float* __restrict__ optr = z ? out1 : out0;
  float* __restrict__ lptr = z ? l1p : l0p;
  const int qbase = blockIdx.x * 128;
  const int tid = threadIdx.x;
  const int w = tid >> 6, lane = tid & 63;
  const int g = lane >> 4, ln = lane & 15;

  // zero junk rows 65..79 of both vv buffers (read by the l-fragment MFMA)
  for (int i = tid; i < 15 * 128; i += 256) {
    vv[0][65 * 128 + i] = 0;
    vv[1][65 * 128 + i] = 0;
  }

  // Q B-frags (col = ln = q-row, k = 8g+j); qh pre-scaled by 0.125*log2e
  bf16x8 qa[2][2];
#pragma unroll
  for (int qf = 0; qf < 2; ++qf) {
    int row = qbase + w * 32 + qf * 16 + ln;
    const unsigned short* qp = qh + (size_t)(b * 4096 + row) * 64;
    qa[qf][0] = *reinterpret_cast<const bf16x8*>(qp + g * 8);
    qa[qf][1] = *reinterpret_cast<const bf16x8*>(qp + 32 + g * 8);
  }

  const f32x4 fz = {0.f, 0.f, 0.f, 0.f};
  f32x4 accO[2][5];
#pragma unroll
  for (int qf = 0; qf < 2; ++qf)
#pragma unroll
    for (int nf = 0; nf < 5; ++nf) accO[qf][nf] = fz;

  const unsigned short* khb = kh + (size_t)b * 4096 * 64;
  const unsigned short* vtb = vt + (size_t)b * 64 * 4096;

  // ---- staging (register prefetch -> swizzled LDS) ----
  bf16x8 kreg[4], vreg[4];
  int mreg = 0;
  auto issue = [&](int ti) {
    int kvbase = kv0 + ti * KVBLK;
#pragma unroll
    for (int i = 0; i < 4; ++i) {
      int c = tid + i * 256;  // V: dv = c>>4, phys kv start (c&15)*8
      vreg[i] = *reinterpret_cast<const bf16x8*>(vtb + (size_t)(c >> 4) * 4096 + kvbase + (c & 15) * 8);
      // K: row = c>>3 (kv), col16 = c&7
      kreg[i] = *reinterpret_cast<const bf16x8*>(khb + (size_t)(kvbase + (c >> 3)) * 64 + (c & 7) * 8);
    }
    if (tid < KVBLK) mreg = mask[b * 4096 + kvbase + tid];
  };
  auto commit = [&](int bs) {
#pragma unroll
    for (int i = 0; i < 4; ++i) {
      int c = tid + i * 256;
      // K swizzled store
      int kbo = ((c >> 3) * 128 + (c & 7) * 16) ^ (((c >> 3) & 7) << 4);
      *reinterpret_cast<bf16x8*>(reinterpret_cast<char*>(kt[bs]) + kbo) = kreg[i];
      // V tau-permuted store (two 8B halves)
      int dv = c >> 4;
      int P0 = (c & 15) * 8;
      int c2 = P0 >> 5, hh = (P0 >> 4) & 1, gg = (P0 >> 2) & 3;
      int x1 = 32 * c2 + 8 * gg + 4 * hh;
      int swz = (dv & 7) << 4;
      union { bf16x8 v; u16x4 h4[2]; } sp; sp.v = vreg[i];
      *reinterpret_cast<u16x4*>(reinterpret_cast<char*>(vv[bs]) + ((dv * 256 + 2 * x1) ^ swz)) = sp.h4[0];
      *reinterpret_cast<u16x4*>(reinterpret_cast<char*>(vv[bs]) + ((dv * 256 + 2 * x1 + 16) ^ swz)) = sp.h4[1];
    }
    if (tid < KVBLK) {
      int p = tid;
      int xx = 32 * (p >> 5) + 8 * ((p >> 2) & 3) + 4 * ((p >> 4) & 1) + (p & 3);
      vv[bs][64 * 128 + xx] = mreg ? (unsigned short)0x3F80 : (unsigned short)0;
    }
  };

  // ---- prologue ----
  issue(0);
  commit(0);
  __syncthreads();
  int cur = 0;

  for (int ti = 0; ti < NT; ++ti) {
    if (ti + 1 < NT) issue(ti + 1);  // loads in flight across compute

    // QK^T swapped: s{qf}[nf][r] = S[kv = nf*16+4g+r][q = qf*16+ln]
    f32x4 s0[8], s1[8];
#pragma unroll
    for (int nf = 0; nf < 8; ++nf) { s0[nf] = fz; s1[nf] = fz; }
    __builtin_amdgcn_s_setprio(1);
#pragma unroll
    for (int c2 = 0; c2 < 2; ++c2)
#pragma unroll
      for (int nf = 0; nf < 8; ++nf) {
        int kvr = nf * 16 + ln;
        int bo = (kvr * 128 + c2 * 64 + g * 16) ^ ((kvr & 7) << 4);
        bf16x8 kf = *reinterpret_cast<const bf16x8*>(reinterpret_cast<const char*>(kt[cur]) + bo);
        s0[nf] = __builtin_amdgcn_mfma_f32_16x16x32_bf16(kf, qa[0][c2], s0[nf], 0, 0, 0);
        s1[nf] = __builtin_amdgcn_mfma_f32_16x16x32_bf16(kf, qa[1][c2], s1[nf], 0, 0, 0);
      }
    __builtin_amdgcn_s_setprio(0);

    // p = exp2(s); pack to PV A-frag words (zero cross-lane via tau)
    unsigned int pw[2][4][4];
#pragma unroll
    for (int c2 = 0; c2 < 4; ++c2)
#pragma unroll
      for (int hh = 0; hh < 2; ++hh) {
        {
          float p0 = __builtin_exp2f(s0[2 * c2 + hh][0]);
          float p1 = __builtin_exp2f(s0[2 * c2 + hh][1]);
          float p2 = __builtin_exp2f(s0[2 * c2 + hh][2]);
          float p3 = __builtin_exp2f(s0[2 * c2 + hh][3]);
          unsigned int w0, w1;
          asm("v_cvt_pk_bf16_f32 %0, %1, %2" : "=v"(w0) : "v"(p0), "v"(p1));
          asm("v_cvt_pk_bf16_f32 %0, %1, %2" : "=v"(w1) : "v"(p2), "v"(p3));
          pw[0][c2][2 * hh] = w0;
          pw[0][c2][2 * hh + 1] = w1;
        }
        {
          float p0 = __builtin_exp2f(s1[2 * c2 + hh][0]);
          float p1 = __builtin_exp2f(s1[2 * c2 + hh][1]);
          float p2 = __builtin_exp2f(s1[2 * c2 + hh][2]);
          float p3 = __builtin_exp2f(s1[2 * c2 + hh][3]);
          unsigned int w0, w1;
          asm("v_cvt_pk_bf16_f32 %0, %1, %2" : "=v"(w0) : "v"(p0), "v"(p1));
          asm("v_cvt_pk_bf16_f32 %0, %1, %2" : "=v"(w1) : "v"(p2), "v"(p3));
          pw[1][c2][2 * hh] = w0;
          pw[1][c2][2 * hh + 1] = w1;
        }
      }

    // PV: O'[q][dv] += P·V  (A = in-reg P, B = vv frags; nf==4 -> l column)
    __builtin_amdgcn_s_setprio(1);
#pragma unroll
    for (int c2 = 0; c2 < 4; ++c2) {
      union { unsigned int u[4]; bf16x8 v; } pa0, pa1;
#pragma unroll
      for (int t = 0; t < 4; ++t) { pa0.u[t] = pw[0][c2][t]; pa1.u[t] = pw[1][c2][t]; }
#pragma unroll
      for (int nf = 0; nf < 5; ++nf) {
        int dvr = nf * 16 + ln;
        int bo = (dvr * 256 + c2 * 64 + g * 16) ^ ((dvr & 7) << 4);
        bf16x8 vb = *reinterpret_cast<const bf16x8*>(reinterpret_cast<const char*>(vv[cur]) + bo);
        accO[0][nf] = __builtin_amdgcn_mfma_f32_16x16x32_bf16(pa0.v, vb, accO[0][nf], 0, 0, 0);
        accO[1][nf] = __builtin_amdgcn_mfma_f32_16x16x32_bf16(pa1.v, vb, accO[1][nf], 0, 0, 0);
      }
    }
    __builtin_amdgcn_s_setprio(0);

    if (ti + 1 < NT) commit(cur ^ 1);
    __syncthreads();
    cur ^= 1;
  }

  // epilogue: raw partial O; l-frag valid at ln==0 lanes (dvr=64 column)
#pragma unroll
  for (int qf = 0; qf < 2; ++qf)
#pragma unroll
    for (int r = 0; r < 4; ++r) {
      int grow = b * 4096 + qbase + w * 32 + qf * 16 + g * 4 + r;
#pragma unroll
      for (int nf = 0; nf < 4; ++nf)
        optr[(size_t)grow * 64 + nf * 16 + ln] = accO[qf][nf][r];
      if (ln == 0) lptr[grow] = accO[qf][4][r];
    }
}

// ---------------- kernel 4: combine partials ----------------
// out = (O0 + O1) / (l0 + l1); 524288 float4s, grid 2048 x 256
__global__ __launch_bounds__(256) void combine_kernel(
    float* __restrict__ out, const float* __restrict__ po1,
    const float* __restrict__ l0p, const float* __restrict__ l1p) {
  int idx = blockIdx.x * 256 + threadIdx.x;
  int row = idx >> 4;  // 16 float4 per 64-col row
  float rl = 1.0f / (l0p[row] + l1p[row]);
  float4 a = reinterpret_cast<float4*>(out)[idx];
  float4 c = reinterpret_cast<const float4*>(po1)[idx];
  a.x = (a.x + c.x) * rl;
  a.y = (a.y + c.y) * rl;
  a.z = (a.z + c.z) * rl;
  a.w = (a.w + c.w) * rl;
  reinterpret_cast<float4*>(out)[idx] = a;
}

extern "C" void kernel_launch(void* const* d_in, const int* in_sizes, int n_in,
                              void* d_out, int out_size, void* d_ws, size_t ws_size,
                              hipStream_t stream) {
  const float* q = (const float*)d_in[0];
  const float* k = (const float*)d_in[1];
  const float* v = (const float*)d_in[2];
  const int* mask = (const int*)d_in[3];
  const float* Wq = (const float*)d_in[4];
  const float* bq = (const float*)d_in[5];
  const float* Wk = (const float*)d_in[6];
  const float* bk = (const float*)d_in[7];
  const float* Wv = (const float*)d_in[8];
  const float* bv = (const float*)d_in[9];

  char* wsb = (char*)d_ws;
  unsigned short* qh = (unsigned short*)(wsb);                    // 4 MiB
  unsigned short* kh = (unsigned short*)(wsb + (4u << 20));       // 4 MiB
  unsigned short* vt = (unsigned short*)(wsb + (8u << 20));       // 4 MiB
  unsigned short* wt = (unsigned short*)(wsb + (12u << 20));      // 192 KiB
  float* po1 = (float*)(wsb + (12u << 20) + 196608);              // 8 MiB
  float* l0p = (float*)(wsb + (12u << 20) + 196608 + (8u << 20)); // 128 KiB
  float* l1p = l0p + 32768;                                       // 128 KiB

  prep_w<<<384, 256, 0, stream>>>(Wq, Wk, Wv, wt);
  proj_kernel<<<dim3(1024, 3), 256, 0, stream>>>(q, k, v, wt, mask, bq, bk, bv, qh, kh, vt);
  attn_kernel<<<dim3(32, 8, 2), 256, 0, stream>>>(qh, kh, vt, mask,
                                                  (float*)d_out, po1, l0p, l1p);
  combine_kernel<<<2048, 256, 0, stream>>>((float*)d_out, po1, l0p, l1p);
}